// Round 9
// baseline (823.763 us; speedup 1.0000x reference)
//
#include <hip/hip_runtime.h>
#include <hip/hip_bf16.h>
#include <stdint.h>

// Problem constants
#define B_    256
#define T_    128
#define W_    32
#define H_    512
#define G4_   2048   // 4*H
#define TW_   96     // warm steps
#define STEPS_ 191   // 96 warm + 95 decode cells
#define TEAMS 16
#define MEMBERS 8
#define ROWS  16     // batch rows per team
#define HC    64     // h-columns per block (8 waves x 8 cols)

typedef __attribute__((ext_vector_type(8))) short short8;
typedef __attribute__((ext_vector_type(4))) float f32x4;
typedef __attribute__((ext_vector_type(4))) uint32_t u32x4;

__device__ __forceinline__ unsigned short f2bf(float f) {
  uint32_t u = __float_as_uint(f);
  u += 0x7fffu + ((u >> 16) & 1u);   // round-to-nearest-even
  return (unsigned short)(u >> 16);
}
__device__ __forceinline__ float sigm(float x) { return 1.f / (1.f + __expf(-x)); }
__device__ __forceinline__ float tanh_(float x) { return 1.f - 2.f / (1.f + __expf(2.f * x)); }

// PROVEN (R6) device-scope primitives: compiler-generated agent atomics for
// the barrier protocol; sc0 sc1 asm only for bulk data (never in spin loops).
#define LOAD_CF(p)      __hip_atomic_load((p), __ATOMIC_RELAXED, __HIP_MEMORY_SCOPE_AGENT)
#define LOAD_CI(p)      __hip_atomic_load((p), __ATOMIC_RELAXED, __HIP_MEMORY_SCOPE_AGENT)
#define ARRIVE(p)       __hip_atomic_fetch_add((p), 1, __ATOMIC_RELAXED, __HIP_MEMORY_SCOPE_AGENT)

__device__ __forceinline__ u32x4 ld16c(const void* p) {
  u32x4 v;
  asm volatile("global_load_dwordx4 %0, %1, off sc0 sc1"
               : "=&v"(v) : "v"(p) : "memory");
  return v;   // caller batches, then s_waitcnt vmcnt(0) + sched_barrier
}
__device__ __forceinline__ void st16c(void* p, u32x4 v) {
  asm volatile("global_store_dwordx4 %0, %1, off sc0 sc1" :: "v"(p), "v"(v) : "memory");
}
__device__ __forceinline__ void stf16c(void* p, f32x4 v) {
  asm volatile("global_store_dwordx4 %0, %1, off sc0 sc1" :: "v"(p), "v"(v) : "memory");
}

// ---------------------------------------------------------------------------
// Persistent LSTM. 128 blocks x 512 threads (8 waves, 1 block/CU).
// team = blockIdx&15 (rows team*16..+16), member = blockIdx>>4 (cols member*64)
// Wave w owns 8 h-cols x 4 gates. Transposed MFMA: A = Wr^T frags (VGPRs),
// B = h^T from LDS. All 4 gates of one cell in one lane => in-register cell.
// Exchange: coalesced sc0sc1 dwordx4; barrier = ONE agent atomicAdd per block
// into a per-team monotonic counter after vmcnt drain + block sync; single
// poller thread per block using agent-scope atomic loads (L1-safe).
// ---------------------------------------------------------------------------
__global__ __launch_bounds__(512, 1) void lstm_kernel(
    const float* __restrict__ inputs, const float* __restrict__ Wk,
    const float* __restrict__ Wr, const float* __restrict__ bias,
    const float* __restrict__ Ww, const float* __restrict__ bw,
    unsigned short* __restrict__ h0buf, unsigned short* __restrict__ h1buf,
    float* __restrict__ pp0, float* __restrict__ pp1,
    unsigned short* __restrict__ warm, int* __restrict__ flags,
    float* __restrict__ out_pred)
{
  const int team = blockIdx.x & 15;
  const int member = blockIdx.x >> 4;   // 0..7
  const int rbase = team * ROWS;
  const int hbase = member * HC;
  const int tid = threadIdx.x;
  const int wave = tid >> 6;            // 0..7
  const int lane = tid & 63;
  const int l4 = lane >> 4, l16 = lane & 15;

  __shared__ unsigned short h_lds[ROWS][H_];              // 16KB, XOR swizzled
  __shared__ float x_all[TW_][ROWS][2];                   // 12KB warm inputs
  __shared__ float x_lds[ROWS][2];                        // decode x (pred)
  __shared__ float pp_lds[8][ROWS][2];                    // per-wave partials
  __shared__ alignas(16) unsigned short h_out[ROWS][HC];  // 2KB repack

  for (int i = tid; i < TW_*ROWS*2; i += 512) {
    int tt = i >> 5, row = (i >> 1) & 15, c = i & 1;
    x_all[tt][row][c] = inputs[(size_t)(rbase+row)*(T_*2) + (W_+tt)*2 + c];
  }

  // ---- persistent per-lane constants (same per-wave math as R4-R6) ----
  const int gateL = l16 & 3, hclL = l16 >> 2;
  short8 afrag[2][16];          // Wr^T fragments: 128 VGPRs
  float bbv[2][4], wk0v[2][4], wk1v[2][4], wwv[2][2];
#pragma unroll
  for (int a = 0; a < 2; a++) {
    const int gcA = gateL*H_ + hbase + wave*8 + a*4 + hclL;
#pragma unroll
    for (int ks = 0; ks < 16; ks++) {
      const float* wp = Wr + (size_t)(ks*32 + l4*8) * G4_ + gcA;
#pragma unroll
      for (int j = 0; j < 8; j++) afrag[a][ks][j] = (short)f2bf(wp[(size_t)j * G4_]);
    }
    const int colA = hbase + wave*8 + a*4 + l4;
#pragma unroll
    for (int j = 0; j < 4; j++) {
      int gcj = j*H_ + colA;
      bbv[a][j] = bias[gcj]; wk0v[a][j] = Wk[gcj]; wk1v[a][j] = Wk[G4_ + gcj];
    }
    wwv[a][0] = Ww[2*colA]; wwv[a][1] = Ww[2*colA + 1];
  }
  const float bwc0 = bw[0], bwc1 = bw[1];
  float creg[2] = {0.f, 0.f};
  __syncthreads();

  int* ctr = flags + team * 16;                 // 64B-spaced step counter
  const int srow = tid >> 5, sg = tid & 31;     // h-stage: 32 thr/row, 2x16B each

  for (int t = 0; t < STEPS_; t++) {
    const unsigned short* hprev = (t & 1) ? h1buf : h0buf;
    unsigned short* hnext = (t & 1) ? h0buf : h1buf;
    const float* ppprev = (t & 1) ? pp1 : pp0;
    float* ppnext = (t & 1) ? pp0 : pp1;

    // ---- phase A: issue ALL coherent loads, one wait, then LDS fill ----
    const bool dox = (t >= TW_) && (tid < 32);
    float vals[MEMBERS];
    if (dox) {
      int row = tid >> 1, c = tid & 1;
      const float* pps = ppprev + (size_t)team*MEMBERS*32 + row*2 + c;
#pragma unroll
      for (int m = 0; m < MEMBERS; m++) vals[m] = LOAD_CF(pps + m*32);
    }
    u32x4 q0, q1;
    {
      const unsigned short* srcb = hprev + (size_t)(rbase+srow)*H_ + sg*8;
      q0 = ld16c(srcb);             // granule sg
      q1 = ld16c(srcb + 256);       // granule sg+32
    }
    asm volatile("s_waitcnt vmcnt(0)" ::: "memory");
    __builtin_amdgcn_sched_barrier(0);
    *(u32x4*)&h_lds[srow][(sg        ^ (srow & 7)) * 8] = q0;
    *(u32x4*)&h_lds[srow][((sg + 32) ^ (srow & 7)) * 8] = q1;
    if (dox) {
      int row = tid >> 1, c = tid & 1;
      float s = c ? bwc1 : bwc0;
#pragma unroll
      for (int m = 0; m < MEMBERS; m++) s += vals[m];
      x_lds[row][c] = s;
      if (member == 0)
        out_pred[((size_t)(rbase+row)*96 + (t - TW_))*2 + c] = s;
    }
    __syncthreads();   // S1

    // ---- phase B: z^T = Wr^T @ h^T (+ bias + Wk*x), MFMA over K=512 ----
    f32x4 acc[2];
    const float* xsrc = (t < TW_) ? &x_all[t][0][0] : &x_lds[0][0];
    {
      float x0 = xsrc[2*l16], x1 = xsrc[2*l16 + 1];
#pragma unroll
      for (int a = 0; a < 2; a++)
#pragma unroll
        for (int j = 0; j < 4; j++)
          acc[a][j] = bbv[a][j] + wk0v[a][j]*x0 + wk1v[a][j]*x1;
    }
#pragma unroll
    for (int ks = 0; ks < 16; ks++) {
      int pg = ((ks*4 + l4) ^ (l16 & 7)) * 8;
      short8 b0 = *(const short8*)&h_lds[l16][pg];
      acc[0] = __builtin_amdgcn_mfma_f32_16x16x32_bf16(afrag[0][ks], b0, acc[0], 0,0,0);
      acc[1] = __builtin_amdgcn_mfma_f32_16x16x32_bf16(afrag[1][ks], b0, acc[1], 0,0,0);
    }

    // ---- phase C: in-register cell update -> h_out + pred partials ----
    float pp0v = 0.f, pp1v = 0.f;
#pragma unroll
    for (int a = 0; a < 2; a++) {
      float zi = acc[a][0], zf = acc[a][1], zg = acc[a][2], zo = acc[a][3];
      float cn = sigm(zf)*creg[a] + sigm(zi)*tanh_(zg);
      float hn = sigm(zo)*tanh_(cn);
      creg[a] = cn;
      pp0v += hn * wwv[a][0];
      pp1v += hn * wwv[a][1];
      h_out[l16][wave*8 + a*4 + l4] = f2bf(hn);
    }
    if (t >= TW_ - 1) {
      pp0v += __shfl_xor(pp0v, 16); pp0v += __shfl_xor(pp0v, 32);
      pp1v += __shfl_xor(pp1v, 16); pp1v += __shfl_xor(pp1v, 32);
      if (l4 == 0) {
        pp_lds[wave][l16][0] = pp0v;
        pp_lds[wave][l16][1] = pp1v;
      }
    }
    __syncthreads();   // S2

    // ---- phase D: coalesced coherent stores ----
    if (tid < 128) {                       // h: 16 rows x 128B, 16B/lane
      int row = tid >> 3, qd = tid & 7;
      u32x4 v = *(const u32x4*)&h_out[row][qd*8];
      st16c(hnext + (size_t)(rbase+row)*H_ + hbase + qd*8, v);
      if (t == TW_ - 1)
        *(u32x4*)(warm + (size_t)(rbase+row)*H_ + hbase + qd*8) = v;
    }
    if (t >= TW_ - 1 && tid < 8) {         // pp: 128B contiguous per block
      f32x4 pv;
#pragma unroll
      for (int j = 0; j < 4; j++) {
        int idx = tid*4 + j, row = idx >> 1, c = idx & 1;
        float s = 0.f;
#pragma unroll
        for (int w8 = 0; w8 < 8; w8++) s += pp_lds[w8][row][c];
        pv[j] = s;
      }
      stf16c(ppnext + (size_t)(team*MEMBERS + member)*32 + tid*4, pv);
    }

    // ---- barrier: drain, ONE arrive per block, single poller, release ----
    asm volatile("s_waitcnt vmcnt(0)" ::: "memory");
    __syncthreads();   // S3: every wave's stores at the coherence point
    if (tid == 0) {
      ARRIVE(ctr);
      int need = MEMBERS * (t + 1);
      while (LOAD_CI(ctr) < need) {}
    }
    __syncthreads();   // S4
  }

  // ---- final pred (k=95) from pp of step 190 (pp1 side) ----
  if (member == 0 && tid < 32) {
    int row = tid >> 1, c = tid & 1;
    const float* pps = pp1 + (size_t)team*MEMBERS*32 + row*2 + c;
    float s = c ? bwc1 : bwc0;
#pragma unroll
    for (int m = 0; m < MEMBERS; m++) s += LOAD_CF(pps + m*32);
    out_pred[((size_t)(rbase+row)*96 + 95)*2 + c] = s;
  }
}

// ---------------------------------------------------------------------------
// cat = [warm_out (bf16) | relu(inputs[:, :31] @ Wc + bc)] as bf16 [256][16384]
// ---------------------------------------------------------------------------
__global__ void build_cat_kernel(
    const float* __restrict__ inputs, const float* __restrict__ Wc,
    const float* __restrict__ bc, const unsigned short* __restrict__ warm,
    unsigned short* __restrict__ cat)
{
  int idx = (blockIdx.x * 256 + threadIdx.x) * 4;   // 4096 blocks
  int b = idx >> 14, k0 = idx & 16383;
  uint2 out;
  if (k0 < 512) {
    out = *(const uint2*)(warm + (size_t)b*512 + k0);
  } else {
    int kk = k0 - 512;
    int w = kk >> 9;
    int hc = kk & 511;
    float x0 = inputs[(size_t)b*256 + w*2], x1 = inputs[(size_t)b*256 + w*2 + 1];
    unsigned short v[4];
#pragma unroll
    for (int j = 0; j < 4; j++) {
      float val = x0 * Wc[hc+j] + x1 * Wc[512 + hc + j] + bc[hc+j];
      v[j] = f2bf(fmaxf(val, 0.f));
    }
    out.x = (uint32_t)v[0] | ((uint32_t)v[1] << 16);
    out.y = (uint32_t)v[2] | ((uint32_t)v[3] << 16);
  }
  *(uint2*)(cat + idx) = out;
}

// ---------------------------------------------------------------------------
// Transposed GEMM: partialT[kc][n][b] = sum_k Wcc[k][n]*cat[b][k] over k-chunk.
// ---------------------------------------------------------------------------
__global__ __launch_bounds__(256, 1) void gemm_kernel(
    const unsigned short* __restrict__ cat, const float* __restrict__ Wcc,
    float* __restrict__ partialT)
{
  const int nc = blockIdx.x & 15;
  const int kc = blockIdx.x >> 4;
  const int tid = threadIdx.x;
  const int w = tid >> 6, lane = tid & 63;
  const int l4 = lane >> 4, l16 = lane & 15;

  f32x4 zero = {0.f, 0.f, 0.f, 0.f};
  f32x4 acc[16];
#pragma unroll
  for (int i = 0; i < 16; i++) acc[i] = zero;

  const int kbase = kc * 2048;
  const int nrow = nc*64 + w*16 + l16;

  for (int ks = 0; ks < 64; ks++) {
    const float* wp = Wcc + (size_t)(kbase + ks*32 + l4*8) * 1024 + nrow;
    short8 af;
#pragma unroll
    for (int j = 0; j < 8; j++) af[j] = (short)f2bf(wp[(size_t)j * 1024]);
    const unsigned short* cp = cat + kbase + ks*32 + l4*8;
#pragma unroll
    for (int bt = 0; bt < 16; bt++) {
      short8 bf = *(const short8*)(cp + (size_t)(bt*16 + l16) * 16384);
      acc[bt] = __builtin_amdgcn_mfma_f32_16x16x32_bf16(af, bf, acc[bt], 0, 0, 0);
    }
  }

  float* pp = partialT + (size_t)kc*1024*256 + (size_t)(nc*64 + w*16 + l4*4)*256 + l16;
#pragma unroll
  for (int bt = 0; bt < 16; bt++) {
#pragma unroll
    for (int r = 0; r < 4; r++)
      pp[(size_t)r*256 + bt*16] = acc[bt][r];
  }
}

// ctT[n][b] = relu(bcc[n] + sum_p partialT[p][n][b]); also copies the
// inputs-passthrough output (saves a separate memcpy launch).
__global__ void reduce_kernel(const float* __restrict__ partialT,
                              const float* __restrict__ bcc, float* __restrict__ ctT,
                              const float* __restrict__ inputs, float* __restrict__ out)
{
  int e = blockIdx.x * 256 + threadIdx.x;   // 1024 blocks
  int n = e >> 8;
  float s = bcc[n];
#pragma unroll
  for (int p = 0; p < 8; p++) s += partialT[(size_t)p*262144 + e];
  ctT[e] = fmaxf(s, 0.f);
  if (e < 65536) out[49920 + e] = inputs[e];
}

// cost/prob heads: one wave per batch row
__global__ void head_kernel(const float* __restrict__ ctT, const float* __restrict__ Wp,
                            const float* __restrict__ bp, const float* __restrict__ Wco,
                            const float* __restrict__ bco, float* __restrict__ out)
{
  int b = blockIdx.x;
  int lane = threadIdx.x;
  float p0 = 0.f, p1 = 0.f, pc = 0.f;
#pragma unroll
  for (int i = 0; i < 16; i++) {
    int n = i*64 + lane;
    float c = ctT[(size_t)n*256 + b];
    p0 += c * Wp[2*n]; p1 += c * Wp[2*n+1]; pc += c * Wco[n];
  }
  for (int m = 1; m < 64; m <<= 1) {
    p0 += __shfl_xor(p0, m); p1 += __shfl_xor(p1, m); pc += __shfl_xor(pc, m);
  }
  if (lane == 0) {
    out[49152 + b]       = pc + bco[0];
    out[49408 + 2*b]     = 1.f / (1.f + __expf(-(p0 + bp[0])));
    out[49408 + 2*b + 1] = 1.f / (1.f + __expf(-(p1 + bp[1])));
  }
}

// ---------------------------------------------------------------------------
extern "C" void kernel_launch(void* const* d_in, const int* in_sizes, int n_in,
                              void* d_out, int out_size, void* d_ws, size_t ws_size,
                              hipStream_t stream) {
  const float* inputs = (const float*)d_in[0];
  const float* Wk   = (const float*)d_in[1];
  const float* Wr   = (const float*)d_in[2];
  const float* bias = (const float*)d_in[3];
  const float* Ww   = (const float*)d_in[4];
  const float* bw   = (const float*)d_in[5];
  const float* Wc   = (const float*)d_in[6];
  const float* bc   = (const float*)d_in[7];
  const float* Wcc  = (const float*)d_in[8];
  const float* bcc  = (const float*)d_in[9];
  const float* Wp   = (const float*)d_in[10];
  const float* bp   = (const float*)d_in[11];
  const float* Wco  = (const float*)d_in[12];
  const float* bco  = (const float*)d_in[13];
  float* out = (float*)d_out;
  char* ws = (char*)d_ws;

  // ws layout (bytes):
  // [0x000000) h0 256KB | [0x040000) flags 8KB | [0x042000) h1 256KB
  // [0x082000) warm 256KB | [0x0C2000) cat 8MB (pp0 aliases cat[0:16KB],
  //   pp1 cat[16KB:32KB]; pp used only during lstm, cat built after) |
  // [0x8C2000) partialT 8MB | [0x10C2000) ctT 1MB
  unsigned short* h0   = (unsigned short*)(ws);
  int*            flags= (int*)(ws + 0x40000);
  unsigned short* h1   = (unsigned short*)(ws + 0x42000);
  unsigned short* warm = (unsigned short*)(ws + 0x82000);
  unsigned short* cat  = (unsigned short*)(ws + 0xC2000);
  float*          pp0  = (float*)(ws + 0xC2000);
  float*          pp1  = (float*)(ws + 0xC6000);
  float*          partialT = (float*)(ws + 0x8C2000);
  float*          ctT  = (float*)(ws + 0x10C2000);

  // zero h0 + flags (re-done every launch; ws not re-poisoned between replays)
  hipMemsetAsync(d_ws, 0, 0x42000, stream);

  lstm_kernel<<<TEAMS*MEMBERS, 512, 0, stream>>>(inputs, Wk, Wr, bias, Ww, bw,
                                                 h0, h1, pp0, pp1, warm, flags, out);
  build_cat_kernel<<<4096, 256, 0, stream>>>(inputs, Wc, bc, warm, cat);
  gemm_kernel<<<128, 256, 0, stream>>>(cat, Wcc, partialT);
  reduce_kernel<<<1024, 256, 0, stream>>>(partialT, bcc, ctT, inputs, out);
  head_kernel<<<256, 64, 0, stream>>>(ctT, Wp, bp, Wco, bco, out);
}

// Round 10
// 750.869 us; speedup vs baseline: 1.0971x; 1.0971x over previous
//
#include <hip/hip_runtime.h>
#include <hip/hip_bf16.h>
#include <stdint.h>

// Problem constants
#define B_    256
#define T_    128
#define W_    32
#define H_    512
#define G4_   2048   // 4*H
#define TW_   96     // warm steps
#define STEPS_ 191   // 96 warm + 95 decode cells
#define TEAMS 16
#define MEMBERS 16
#define ROWS  16     // batch rows per team
#define HC    32     // h-columns per block

typedef __attribute__((ext_vector_type(8))) short short8;
typedef __attribute__((ext_vector_type(4))) float f32x4;
typedef __attribute__((ext_vector_type(4))) uint32_t u32x4;

__device__ __forceinline__ unsigned short f2bf(float f) {
  uint32_t u = __float_as_uint(f);
  u += 0x7fffu + ((u >> 16) & 1u);   // round-to-nearest-even
  return (unsigned short)(u >> 16);
}
__device__ __forceinline__ float sigm(float x) { return 1.f / (1.f + __expf(-x)); }
__device__ __forceinline__ float tanh_(float x) { return 1.f - 2.f / (1.f + __expf(2.f * x)); }

// PROVEN (R6) device-scope primitives: compiler agent atomics for the barrier
// protocol; sc0 sc1 asm (early-clobber outputs) only for bulk data.
#define LOAD_CF(p)      __hip_atomic_load((p), __ATOMIC_RELAXED, __HIP_MEMORY_SCOPE_AGENT)
#define LOAD_CI(p)      __hip_atomic_load((p), __ATOMIC_RELAXED, __HIP_MEMORY_SCOPE_AGENT)
#define ARRIVE(p)       __hip_atomic_fetch_add((p), 1, __ATOMIC_RELAXED, __HIP_MEMORY_SCOPE_AGENT)

__device__ __forceinline__ u32x4 ld16c(const void* p) {
  u32x4 v;
  asm volatile("global_load_dwordx4 %0, %1, off sc0 sc1"
               : "=&v"(v) : "v"(p) : "memory");
  return v;   // caller batches, then s_waitcnt vmcnt(0) + sched_barrier
}
__device__ __forceinline__ void st16c(void* p, u32x4 v) {
  asm volatile("global_store_dwordx4 %0, %1, off sc0 sc1" :: "v"(p), "v"(v) : "memory");
}
__device__ __forceinline__ void stf16c(void* p, f32x4 v) {
  asm volatile("global_store_dwordx4 %0, %1, off sc0 sc1" :: "v"(p), "v"(v) : "memory");
}

struct LSmem {                                   // LSTM role (~29.5KB)
  unsigned short h_lds[ROWS][H_];                // 16KB, XOR swizzled
  float x_all[TW_][ROWS][2];                     // 12KB warm inputs
  float x_lds[ROWS][2];
  float pp_lds[4][ROWS][2];
  alignas(16) unsigned short h_out[ROWS][HC];    // 1KB repack
};
struct GSmem {                                   // GEMM role (~16KB)
  float wc0[512], wc1[512], bcl[512];
  float xin[256][10];                            // per-row x pairs, w0..w0+4
};
union Smem { LSmem l; GSmem g; };

// ---------------------------------------------------------------------------
// Mega kernel, grid 384 x 256:
//  blocks [0,256): persistent LSTM (verbatim R6 structure, 532us proven)
//  blocks [256,384): big-GEMM for K in [512,16384) — depends only on
//    inputs/Wc/bc/Wcc, runs concurrently in the LSTM's idle issue slots.
//    B-operand (cat) is computed on the fly: relu(x@Wc+bc) -> bf16.
// Co-residency by CAPACITY (2 blocks/CU fits LDS+VGPR), not dispatch order.
// ---------------------------------------------------------------------------
__global__ __launch_bounds__(256, 1) void mega_kernel(
    const float* __restrict__ inputs, const float* __restrict__ Wk,
    const float* __restrict__ Wr, const float* __restrict__ bias,
    const float* __restrict__ Ww, const float* __restrict__ bw,
    const float* __restrict__ Wc, const float* __restrict__ bc,
    const float* __restrict__ Wcc,
    unsigned short* __restrict__ h0buf, unsigned short* __restrict__ h1buf,
    float* __restrict__ pp0, float* __restrict__ pp1,
    unsigned short* __restrict__ warm, int* __restrict__ flags,
    float* __restrict__ partialT, float* __restrict__ out_pred)
{
  __shared__ Smem sm;
  const int tid = threadIdx.x;
  const int wave = tid >> 6;
  const int lane = tid & 63;
  const int l4 = lane >> 4, l16 = lane & 15;

  if (blockIdx.x >= 256) {
    // ================= GEMM role =================
    const int gb = blockIdx.x - 256;       // 0..127
    const int nc = gb & 15, kc = gb >> 4;  // 16 n-chunks x 8 k-chunks
    const int koff = (kc == 0) ? 0 : kc*2048 - 512;   // kk = k-512 base
    const int nks  = (kc == 0) ? 48 : 64;             // kk count /32
    const int w0 = koff >> 9;
    const int nw = (kc == 0) ? 3 : 5;
    for (int i = tid; i < 512; i += 256) {
      sm.g.wc0[i] = Wc[i]; sm.g.wc1[i] = Wc[512 + i]; sm.g.bcl[i] = bc[i];
    }
    for (int i = tid; i < 256*nw*2; i += 256) {
      int row = i / (nw*2), r = i - row*(nw*2);
      sm.g.xin[row][r] = inputs[(size_t)row*(T_*2) + w0*2 + r];
    }
    __syncthreads();

    const int nrow = nc*64 + wave*16 + l16;
    f32x4 zero = {0.f,0.f,0.f,0.f};
    f32x4 acc[16];
#pragma unroll
    for (int i = 0; i < 16; i++) acc[i] = zero;

    for (int ks = 0; ks < nks; ks++) {
      const int kkl = koff + ks*32 + l4*8;
      const float* wp = Wcc + (size_t)(512 + kkl) * 1024 + nrow;
      short8 af;
#pragma unroll
      for (int j = 0; j < 8; j++) af[j] = (short)f2bf(wp[(size_t)j * 1024]);
      const int w = kkl >> 9, hc = kkl & 511;
      const int wi = (w - w0)*2;
      float c0[8], c1[8], cb[8];
#pragma unroll
      for (int j = 0; j < 8; j++) {
        c0[j] = sm.g.wc0[hc+j]; c1[j] = sm.g.wc1[hc+j]; cb[j] = sm.g.bcl[hc+j];
      }
#pragma unroll
      for (int bt = 0; bt < 16; bt++) {
        int row = bt*16 + l16;
        float x0 = sm.g.xin[row][wi], x1 = sm.g.xin[row][wi+1];
        short8 bf;
#pragma unroll
        for (int j = 0; j < 8; j++) {
          float v = fmaf(x0, c0[j], fmaf(x1, c1[j], cb[j]));
          bf[j] = (short)f2bf(fmaxf(v, 0.f));
        }
        acc[bt] = __builtin_amdgcn_mfma_f32_16x16x32_bf16(af, bf, acc[bt], 0,0,0);
      }
    }
    float* pp = partialT + (size_t)kc*262144 + (size_t)(nc*64 + wave*16 + l4*4)*256 + l16;
#pragma unroll
    for (int bt = 0; bt < 16; bt++)
#pragma unroll
      for (int r = 0; r < 4; r++)
        pp[(size_t)r*256 + bt*16] = acc[bt][r];
    return;
  }

  // ================= LSTM role (verbatim R6) =================
  const int team = blockIdx.x & 15;
  const int member = blockIdx.x >> 4;   // 0..15
  const int rbase = team * ROWS;
  const int hbase = member * HC;

  for (int i = tid; i < TW_*ROWS*2; i += 256) {
    int tt = i >> 5, row = (i >> 1) & 15, c = i & 1;
    sm.l.x_all[tt][row][c] = inputs[(size_t)(rbase+row)*(T_*2) + (W_+tt)*2 + c];
  }

  const int gateL = l16 & 3, hclL = l16 >> 2;
  short8 afrag[2][16];          // Wr^T fragments: 128 VGPRs
  float bbv[2][4], wk0v[2][4], wk1v[2][4], wwv[2][2];
#pragma unroll
  for (int a = 0; a < 2; a++) {
    const int gcA = gateL*H_ + hbase + wave*8 + a*4 + hclL;
#pragma unroll
    for (int ks = 0; ks < 16; ks++) {
      const float* wp = Wr + (size_t)(ks*32 + l4*8) * G4_ + gcA;
#pragma unroll
      for (int j = 0; j < 8; j++) afrag[a][ks][j] = (short)f2bf(wp[(size_t)j * G4_]);
    }
    const int colA = hbase + wave*8 + a*4 + l4;
#pragma unroll
    for (int j = 0; j < 4; j++) {
      int gcj = j*H_ + colA;
      bbv[a][j] = bias[gcj]; wk0v[a][j] = Wk[gcj]; wk1v[a][j] = Wk[G4_ + gcj];
    }
    wwv[a][0] = Ww[2*colA]; wwv[a][1] = Ww[2*colA + 1];
  }
  const float bwc0 = bw[0], bwc1 = bw[1];
  float creg[2] = {0.f, 0.f};
  __syncthreads();

  int* ctr = flags + team * 16;                 // 64B-spaced step counter
  const int srow = tid >> 4, sg = tid & 15;     // h-stage: 16 thr/row, 4x16B

  for (int t = 0; t < STEPS_; t++) {
    const unsigned short* hprev = (t & 1) ? h1buf : h0buf;
    unsigned short* hnext = (t & 1) ? h0buf : h1buf;
    const float* ppprev = (t & 1) ? pp1 : pp0;
    float* ppnext = (t & 1) ? pp0 : pp1;

    // ---- phase A: issue ALL coherent loads, one wait, then LDS fill ----
    const bool dox = (t >= TW_) && (tid < 32);
    float vals[MEMBERS];
    if (dox) {
      int row = tid >> 1, c = tid & 1;
      const float* pps = ppprev + (size_t)team*MEMBERS*32 + row*2 + c;
#pragma unroll
      for (int m = 0; m < MEMBERS; m++) vals[m] = LOAD_CF(pps + m*32);
    }
    u32x4 q[4];
    {
      const unsigned short* srcb = hprev + (size_t)(rbase+srow)*H_ + sg*8;
#pragma unroll
      for (int i = 0; i < 4; i++) q[i] = ld16c(srcb + i*128);   // granule sg+16i
    }
    asm volatile("s_waitcnt vmcnt(0)" ::: "memory");
    __builtin_amdgcn_sched_barrier(0);
#pragma unroll
    for (int i = 0; i < 4; i++)
      *(u32x4*)&sm.l.h_lds[srow][((sg + 16*i) ^ (srow & 7)) * 8] = q[i];
    if (dox) {
      int row = tid >> 1, c = tid & 1;
      float s = c ? bwc1 : bwc0;
#pragma unroll
      for (int m = 0; m < MEMBERS; m++) s += vals[m];
      sm.l.x_lds[row][c] = s;
      if (member == 0)
        out_pred[((size_t)(rbase+row)*96 + (t - TW_))*2 + c] = s;
    }
    __syncthreads();   // S1

    // ---- phase B: z^T = Wr^T @ h^T (+ bias + Wk*x), MFMA over K=512 ----
    f32x4 acc[2];
    const float* xsrc = (t < TW_) ? &sm.l.x_all[t][0][0] : &sm.l.x_lds[0][0];
    {
      float x0 = xsrc[2*l16], x1 = xsrc[2*l16 + 1];
#pragma unroll
      for (int a = 0; a < 2; a++)
#pragma unroll
        for (int j = 0; j < 4; j++)
          acc[a][j] = bbv[a][j] + wk0v[a][j]*x0 + wk1v[a][j]*x1;
    }
#pragma unroll
    for (int ks = 0; ks < 16; ks++) {
      int pg = ((ks*4 + l4) ^ (l16 & 7)) * 8;
      short8 b0 = *(const short8*)&sm.l.h_lds[l16][pg];
      acc[0] = __builtin_amdgcn_mfma_f32_16x16x32_bf16(afrag[0][ks], b0, acc[0], 0,0,0);
      acc[1] = __builtin_amdgcn_mfma_f32_16x16x32_bf16(afrag[1][ks], b0, acc[1], 0,0,0);
    }

    // ---- phase C: in-register cell update -> h_out + pred partials ----
    float pp0v = 0.f, pp1v = 0.f;
#pragma unroll
    for (int a = 0; a < 2; a++) {
      float zi = acc[a][0], zf = acc[a][1], zg = acc[a][2], zo = acc[a][3];
      float cn = sigm(zf)*creg[a] + sigm(zi)*tanh_(zg);
      float hn = sigm(zo)*tanh_(cn);
      creg[a] = cn;
      pp0v += hn * wwv[a][0];
      pp1v += hn * wwv[a][1];
      sm.l.h_out[l16][wave*8 + a*4 + l4] = f2bf(hn);
    }
    if (t >= TW_ - 1) {
      pp0v += __shfl_xor(pp0v, 16); pp0v += __shfl_xor(pp0v, 32);
      pp1v += __shfl_xor(pp1v, 16); pp1v += __shfl_xor(pp1v, 32);
      if (l4 == 0) {
        sm.l.pp_lds[wave][l16][0] = pp0v;
        sm.l.pp_lds[wave][l16][1] = pp1v;
      }
    }
    __syncthreads();   // S2

    // ---- phase D: coalesced coherent stores ----
    if (tid < 64) {                        // h: 16 rows x 64B, 16B/lane
      int row = tid >> 2, qd = tid & 3;
      u32x4 v = *(const u32x4*)&sm.l.h_out[row][qd*8];
      st16c(hnext + (size_t)(rbase+row)*H_ + hbase + qd*8, v);
      if (t == TW_ - 1)
        *(u32x4*)(warm + (size_t)(rbase+row)*H_ + hbase + qd*8) = v;
    }
    if (t >= TW_ - 1 && tid < 8) {         // pp: 128B contiguous per block
      f32x4 pv;
#pragma unroll
      for (int j = 0; j < 4; j++) {
        int idx = tid*4 + j, row = idx >> 1, c = idx & 1;
        pv[j] = sm.l.pp_lds[0][row][c] + sm.l.pp_lds[1][row][c]
              + sm.l.pp_lds[2][row][c] + sm.l.pp_lds[3][row][c];
      }
      stf16c(ppnext + (size_t)(team*MEMBERS + member)*32 + tid*4, pv);
    }

    // ---- barrier: drain, ONE arrive per block, single poller, release ----
    asm volatile("s_waitcnt vmcnt(0)" ::: "memory");
    __syncthreads();   // S3: every wave's stores at the coherence point
    if (tid == 0) {
      ARRIVE(ctr);
      int need = MEMBERS * (t + 1);
      while (LOAD_CI(ctr) < need) {}
    }
    __syncthreads();   // S4
  }

  // ---- final pred (k=95) from pp of step 190 (pp1 side) ----
  if (member == 0 && tid < 32) {
    int row = tid >> 1, c = tid & 1;
    const float* pps = pp1 + (size_t)team*MEMBERS*32 + row*2 + c;
    float s = c ? bwc1 : bwc0;
#pragma unroll
    for (int m = 0; m < MEMBERS; m++) s += LOAD_CF(pps + m*32);
    out_pred[((size_t)(rbase+row)*96 + 95)*2 + c] = s;
  }
}

// ---------------------------------------------------------------------------
// Post-lstm: GEMM over K in [0,512) — B = warm_out (bf16), A = Wcc[0:512].
// grid 16 x 256. Writes the 9th partial (1MB).
// ---------------------------------------------------------------------------
__global__ __launch_bounds__(256, 1) void gemm0_kernel(
    const unsigned short* __restrict__ warm, const float* __restrict__ Wcc,
    float* __restrict__ partial8)
{
  const int nc = blockIdx.x;
  const int tid = threadIdx.x;
  const int w = tid >> 6, lane = tid & 63;
  const int l4 = lane >> 4, l16 = lane & 15;

  f32x4 zero = {0.f,0.f,0.f,0.f};
  f32x4 acc[16];
#pragma unroll
  for (int i = 0; i < 16; i++) acc[i] = zero;

  const int nrow = nc*64 + w*16 + l16;
  for (int ks = 0; ks < 16; ks++) {
    const float* wp = Wcc + (size_t)(ks*32 + l4*8) * 1024 + nrow;
    short8 af;
#pragma unroll
    for (int j = 0; j < 8; j++) af[j] = (short)f2bf(wp[(size_t)j * 1024]);
    const unsigned short* cp = warm + ks*32 + l4*8;
#pragma unroll
    for (int bt = 0; bt < 16; bt++) {
      short8 bf = *(const short8*)(cp + (size_t)(bt*16 + l16) * 512);
      acc[bt] = __builtin_amdgcn_mfma_f32_16x16x32_bf16(af, bf, acc[bt], 0,0,0);
    }
  }
  float* pp = partial8 + (size_t)(nc*64 + w*16 + l4*4)*256 + l16;
#pragma unroll
  for (int bt = 0; bt < 16; bt++)
#pragma unroll
    for (int r = 0; r < 4; r++)
      pp[(size_t)r*256 + bt*16] = acc[bt][r];
}

// ctT[n][b] = relu(bcc[n] + sum_{p<8} partialT[p][n][b] + partial8[n][b]);
// also copies the inputs-passthrough output.
__global__ void reduce_kernel(const float* __restrict__ partialT,
                              const float* __restrict__ partial8,
                              const float* __restrict__ bcc, float* __restrict__ ctT,
                              const float* __restrict__ inputs, float* __restrict__ out)
{
  int e = blockIdx.x * 256 + threadIdx.x;   // 1024 blocks
  int n = e >> 8;
  float s = bcc[n] + partial8[e];
#pragma unroll
  for (int p = 0; p < 8; p++) s += partialT[(size_t)p*262144 + e];
  ctT[e] = fmaxf(s, 0.f);
  if (e < 65536) out[49920 + e] = inputs[e];
}

// cost/prob heads: one wave per batch row
__global__ void head_kernel(const float* __restrict__ ctT, const float* __restrict__ Wp,
                            const float* __restrict__ bp, const float* __restrict__ Wco,
                            const float* __restrict__ bco, float* __restrict__ out)
{
  int b = blockIdx.x;
  int lane = threadIdx.x;
  float p0 = 0.f, p1 = 0.f, pc = 0.f;
#pragma unroll
  for (int i = 0; i < 16; i++) {
    int n = i*64 + lane;
    float c = ctT[(size_t)n*256 + b];
    p0 += c * Wp[2*n]; p1 += c * Wp[2*n+1]; pc += c * Wco[n];
  }
  for (int m = 1; m < 64; m <<= 1) {
    p0 += __shfl_xor(p0, m); p1 += __shfl_xor(p1, m); pc += __shfl_xor(pc, m);
  }
  if (lane == 0) {
    out[49152 + b]       = pc + bco[0];
    out[49408 + 2*b]     = 1.f / (1.f + __expf(-(p0 + bp[0])));
    out[49408 + 2*b + 1] = 1.f / (1.f + __expf(-(p1 + bp[1])));
  }
}

// ---------------------------------------------------------------------------
extern "C" void kernel_launch(void* const* d_in, const int* in_sizes, int n_in,
                              void* d_out, int out_size, void* d_ws, size_t ws_size,
                              hipStream_t stream) {
  const float* inputs = (const float*)d_in[0];
  const float* Wk   = (const float*)d_in[1];
  const float* Wr   = (const float*)d_in[2];
  const float* bias = (const float*)d_in[3];
  const float* Ww   = (const float*)d_in[4];
  const float* bw   = (const float*)d_in[5];
  const float* Wc   = (const float*)d_in[6];
  const float* bc   = (const float*)d_in[7];
  const float* Wcc  = (const float*)d_in[8];
  const float* bcc  = (const float*)d_in[9];
  const float* Wp   = (const float*)d_in[10];
  const float* bp   = (const float*)d_in[11];
  const float* Wco  = (const float*)d_in[12];
  const float* bco  = (const float*)d_in[13];
  float* out = (float*)d_out;
  char* ws = (char*)d_ws;

  // ws layout (bytes):
  // [0x000000) h0 256KB | [0x040000) flags 8KB | [0x042000) h1 256KB
  // [0x082000) warm 256KB | [0x0C2000) pp0 32KB | [0x0CA000) pp1 32KB |
  // [0x0D2000) partial8 1MB | [0x8C2000) partialT 8MB | [0x10C2000) ctT 1MB
  unsigned short* h0   = (unsigned short*)(ws);
  int*            flags= (int*)(ws + 0x40000);
  unsigned short* h1   = (unsigned short*)(ws + 0x42000);
  unsigned short* warm = (unsigned short*)(ws + 0x82000);
  float*          pp0  = (float*)(ws + 0xC2000);
  float*          pp1  = (float*)(ws + 0xCA000);
  float*          partial8 = (float*)(ws + 0xD2000);
  float*          partialT = (float*)(ws + 0x8C2000);
  float*          ctT  = (float*)(ws + 0x10C2000);

  // zero h0 + flags (re-done every launch; ws not re-poisoned between replays)
  hipMemsetAsync(d_ws, 0, 0x42000, stream);

  mega_kernel<<<384, 256, 0, stream>>>(inputs, Wk, Wr, bias, Ww, bw, Wc, bc, Wcc,
                                       h0, h1, pp0, pp1, warm, flags,
                                       partialT, out);
  gemm0_kernel<<<16, 256, 0, stream>>>(warm, Wcc, partial8);
  reduce_kernel<<<1024, 256, 0, stream>>>(partialT, partial8, bcc, ctT, inputs, out);
  head_kernel<<<256, 64, 0, stream>>>(ctT, Wp, bp, Wco, bco, out);
}

// Round 11
// 746.643 us; speedup vs baseline: 1.1033x; 1.0057x over previous
//
#include <hip/hip_runtime.h>
#include <hip/hip_bf16.h>
#include <stdint.h>

// Problem constants
#define B_    256
#define T_    128
#define W_    32
#define H_    512
#define G4_   2048   // 4*H
#define TW_   96     // warm steps
#define STEPS_ 191   // 96 warm + 95 decode cells
#define TEAMS 16
#define MEMBERS 16
#define ROWS  16     // batch rows per team
#define HC    32     // h-columns per block

typedef __attribute__((ext_vector_type(8))) short short8;
typedef __attribute__((ext_vector_type(4))) float f32x4;
typedef __attribute__((ext_vector_type(4))) uint32_t u32x4;

__device__ __forceinline__ unsigned short f2bf(float f) {
  uint32_t u = __float_as_uint(f);
  u += 0x7fffu + ((u >> 16) & 1u);   // round-to-nearest-even
  return (unsigned short)(u >> 16);
}
__device__ __forceinline__ float sigm(float x) { return 1.f / (1.f + __expf(-x)); }
__device__ __forceinline__ float tanh_(float x) { return 1.f - 2.f / (1.f + __expf(2.f * x)); }

// PROVEN (R6) device-scope primitives: compiler agent atomics for the barrier
// protocol; sc0 sc1 asm (early-clobber outputs) only for bulk data.
#define LOAD_CF(p)      __hip_atomic_load((p), __ATOMIC_RELAXED, __HIP_MEMORY_SCOPE_AGENT)
#define LOAD_CI(p)      __hip_atomic_load((p), __ATOMIC_RELAXED, __HIP_MEMORY_SCOPE_AGENT)
#define ARRIVE(p)       __hip_atomic_fetch_add((p), 1, __ATOMIC_RELAXED, __HIP_MEMORY_SCOPE_AGENT)

__device__ __forceinline__ u32x4 ld16c(const void* p) {
  u32x4 v;
  asm volatile("global_load_dwordx4 %0, %1, off sc0 sc1"
               : "=&v"(v) : "v"(p) : "memory");
  return v;   // caller batches, then s_waitcnt vmcnt(0) + sched_barrier
}
__device__ __forceinline__ void st16c(void* p, u32x4 v) {
  asm volatile("global_store_dwordx4 %0, %1, off sc0 sc1" :: "v"(p), "v"(v) : "memory");
}
__device__ __forceinline__ void stf16c(void* p, f32x4 v) {
  asm volatile("global_store_dwordx4 %0, %1, off sc0 sc1" :: "v"(p), "v"(v) : "memory");
}

struct LSmem {                                   // LSTM role (~29.5KB)
  unsigned short h_lds[ROWS][H_];                // 16KB, XOR swizzled
  float x_all[TW_][ROWS][2];                     // 12KB warm inputs
  float x_lds[ROWS][2];
  float pp_lds[4][ROWS][2];
  alignas(16) unsigned short h_out[ROWS][HC];    // 1KB repack
};
struct GSmem {                                   // GEMM role (~16KB)
  float wc0[512], wc1[512], bcl[512];
  float xin[256][10];                            // per-row x pairs, w0..w0+4
};
union Smem { LSmem l; GSmem g; };

// ---------------------------------------------------------------------------
// Mega kernel, grid 512 x 256:
//  blocks [0,256): persistent LSTM (R6 structure) at wave priority 1.
//  blocks [256,512): big-GEMM K in [512,16384), 32 nc x 8 kc, 2 active waves
//    (waves 2-3 exit after the fill barrier) at priority 0 — fills idle
//    issue slots on EVERY CU uniformly; B = relu(x@Wc+bc) built on the fly.
// Co-residency by CAPACITY (any 2 blocks fit a CU's LDS/VGPR), not order.
// ---------------------------------------------------------------------------
__global__ __launch_bounds__(256, 1) void mega_kernel(
    const float* __restrict__ inputs, const float* __restrict__ Wk,
    const float* __restrict__ Wr, const float* __restrict__ bias,
    const float* __restrict__ Ww, const float* __restrict__ bw,
    const float* __restrict__ Wc, const float* __restrict__ bc,
    const float* __restrict__ Wcc,
    unsigned short* __restrict__ h0buf, unsigned short* __restrict__ h1buf,
    float* __restrict__ pp0, float* __restrict__ pp1,
    unsigned short* __restrict__ warm, int* __restrict__ flags,
    float* __restrict__ partialT, float* __restrict__ out_pred)
{
  __shared__ Smem sm;
  const int tid = threadIdx.x;
  const int wave = tid >> 6;
  const int lane = tid & 63;
  const int l4 = lane >> 4, l16 = lane & 15;

  if (blockIdx.x >= 256) {
    // ================= GEMM role (priority 0) =================
    const int gb = blockIdx.x - 256;       // 0..255
    const int nc = gb & 31, kc = gb >> 5;  // 32 n-chunks x 8 k-chunks
    const int koff = (kc == 0) ? 0 : kc*2048 - 512;   // kk = k-512 base
    const int nks  = (kc == 0) ? 48 : 64;             // kk count /32
    const int w0 = koff >> 9;
    const int nw = (kc == 0) ? 3 : 5;
    for (int i = tid; i < 512; i += 256) {
      sm.g.wc0[i] = Wc[i]; sm.g.wc1[i] = Wc[512 + i]; sm.g.bcl[i] = bc[i];
    }
    for (int i = tid; i < 256*nw*2; i += 256) {
      int row = i / (nw*2), r = i - row*(nw*2);
      sm.g.xin[row][r] = inputs[(size_t)row*(T_*2) + w0*2 + r];
    }
    __syncthreads();
    if (wave >= 2) return;                 // 2 active waves per GEMM block

    const int nrow = nc*32 + wave*16 + l16;
    f32x4 zero = {0.f,0.f,0.f,0.f};
    f32x4 acc[16];
#pragma unroll
    for (int i = 0; i < 16; i++) acc[i] = zero;

    for (int ks = 0; ks < nks; ks++) {
      const int kkl = koff + ks*32 + l4*8;
      const float* wp = Wcc + (size_t)(512 + kkl) * 1024 + nrow;
      short8 af;
#pragma unroll
      for (int j = 0; j < 8; j++) af[j] = (short)f2bf(wp[(size_t)j * 1024]);
      const int w = kkl >> 9, hc = kkl & 511;
      const int wi = (w - w0)*2;
      float c0[8], c1[8], cb[8];
#pragma unroll
      for (int j = 0; j < 8; j++) {
        c0[j] = sm.g.wc0[hc+j]; c1[j] = sm.g.wc1[hc+j]; cb[j] = sm.g.bcl[hc+j];
      }
#pragma unroll
      for (int bt = 0; bt < 16; bt++) {
        int row = bt*16 + l16;
        float x0 = sm.g.xin[row][wi], x1 = sm.g.xin[row][wi+1];
        short8 bf;
#pragma unroll
        for (int j = 0; j < 8; j++) {
          float v = fmaf(x0, c0[j], fmaf(x1, c1[j], cb[j]));
          bf[j] = (short)f2bf(fmaxf(v, 0.f));
        }
        acc[bt] = __builtin_amdgcn_mfma_f32_16x16x32_bf16(af, bf, acc[bt], 0,0,0);
      }
    }
    float* pp = partialT + (size_t)kc*262144 + (size_t)(nc*32 + wave*16 + l4*4)*256 + l16;
#pragma unroll
    for (int bt = 0; bt < 16; bt++)
#pragma unroll
      for (int r = 0; r < 4; r++)
        pp[(size_t)r*256 + bt*16] = acc[bt][r];
    return;
  }

  // ================= LSTM role (priority 1) =================
  __builtin_amdgcn_s_setprio(1);
  const int team = blockIdx.x & 15;
  const int member = blockIdx.x >> 4;   // 0..15
  const int rbase = team * ROWS;
  const int hbase = member * HC;

  for (int i = tid; i < TW_*ROWS*2; i += 256) {
    int tt = i >> 5, row = (i >> 1) & 15, c = i & 1;
    sm.l.x_all[tt][row][c] = inputs[(size_t)(rbase+row)*(T_*2) + (W_+tt)*2 + c];
  }

  const int gateL = l16 & 3, hclL = l16 >> 2;
  short8 afrag[2][16];          // Wr^T fragments: 128 VGPRs
  float bbv[2][4], wk0v[2][4], wk1v[2][4], wwv[2][2];
#pragma unroll
  for (int a = 0; a < 2; a++) {
    const int gcA = gateL*H_ + hbase + wave*8 + a*4 + hclL;
#pragma unroll
    for (int ks = 0; ks < 16; ks++) {
      const float* wp = Wr + (size_t)(ks*32 + l4*8) * G4_ + gcA;
#pragma unroll
      for (int j = 0; j < 8; j++) afrag[a][ks][j] = (short)f2bf(wp[(size_t)j * G4_]);
    }
    const int colA = hbase + wave*8 + a*4 + l4;
#pragma unroll
    for (int j = 0; j < 4; j++) {
      int gcj = j*H_ + colA;
      bbv[a][j] = bias[gcj]; wk0v[a][j] = Wk[gcj]; wk1v[a][j] = Wk[G4_ + gcj];
    }
    wwv[a][0] = Ww[2*colA]; wwv[a][1] = Ww[2*colA + 1];
  }
  const float bwc0 = bw[0], bwc1 = bw[1];
  float creg[2] = {0.f, 0.f};
  __syncthreads();

  int* ctr = flags + team * 16;                 // 64B-spaced step counter
  const int srow = tid >> 4, sg = tid & 15;     // h-stage: 16 thr/row, 4x16B

  for (int t = 0; t < STEPS_; t++) {
    const unsigned short* hprev = (t & 1) ? h1buf : h0buf;
    unsigned short* hnext = (t & 1) ? h0buf : h1buf;
    const float* ppprev = (t & 1) ? pp1 : pp0;
    float* ppnext = (t & 1) ? pp0 : pp1;

    // ---- phase A: issue ALL coherent loads, one wait, then LDS fill ----
    const bool dox = (t >= TW_) && (tid < 32);
    float vals[MEMBERS];
    if (dox) {
      int row = tid >> 1, c = tid & 1;
      const float* pps = ppprev + (size_t)team*MEMBERS*32 + row*2 + c;
#pragma unroll
      for (int m = 0; m < MEMBERS; m++) vals[m] = LOAD_CF(pps + m*32);
    }
    u32x4 q[4];
    {
      const unsigned short* srcb = hprev + (size_t)(rbase+srow)*H_ + sg*8;
#pragma unroll
      for (int i = 0; i < 4; i++) q[i] = ld16c(srcb + i*128);   // granule sg+16i
    }
    asm volatile("s_waitcnt vmcnt(0)" ::: "memory");
    __builtin_amdgcn_sched_barrier(0);
#pragma unroll
    for (int i = 0; i < 4; i++)
      *(u32x4*)&sm.l.h_lds[srow][((sg + 16*i) ^ (srow & 7)) * 8] = q[i];
    if (dox) {
      int row = tid >> 1, c = tid & 1;
      float s = c ? bwc1 : bwc0;
#pragma unroll
      for (int m = 0; m < MEMBERS; m++) s += vals[m];
      sm.l.x_lds[row][c] = s;
      if (member == 0)
        out_pred[((size_t)(rbase+row)*96 + (t - TW_))*2 + c] = s;
    }
    __syncthreads();   // S1

    // ---- phase B: z^T = Wr^T @ h^T (+ bias + Wk*x), MFMA over K=512 ----
    f32x4 acc[2];
    const float* xsrc = (t < TW_) ? &sm.l.x_all[t][0][0] : &sm.l.x_lds[0][0];
    {
      float x0 = xsrc[2*l16], x1 = xsrc[2*l16 + 1];
#pragma unroll
      for (int a = 0; a < 2; a++)
#pragma unroll
        for (int j = 0; j < 4; j++)
          acc[a][j] = bbv[a][j] + wk0v[a][j]*x0 + wk1v[a][j]*x1;
    }
#pragma unroll
    for (int ks = 0; ks < 16; ks++) {
      int pg = ((ks*4 + l4) ^ (l16 & 7)) * 8;
      short8 b0 = *(const short8*)&sm.l.h_lds[l16][pg];
      acc[0] = __builtin_amdgcn_mfma_f32_16x16x32_bf16(afrag[0][ks], b0, acc[0], 0,0,0);
      acc[1] = __builtin_amdgcn_mfma_f32_16x16x32_bf16(afrag[1][ks], b0, acc[1], 0,0,0);
    }

    // ---- phase C: in-register cell update -> h_out + pred partials ----
    float pp0v = 0.f, pp1v = 0.f;
#pragma unroll
    for (int a = 0; a < 2; a++) {
      float zi = acc[a][0], zf = acc[a][1], zg = acc[a][2], zo = acc[a][3];
      float cn = sigm(zf)*creg[a] + sigm(zi)*tanh_(zg);
      float hn = sigm(zo)*tanh_(cn);
      creg[a] = cn;
      pp0v += hn * wwv[a][0];
      pp1v += hn * wwv[a][1];
      sm.l.h_out[l16][wave*8 + a*4 + l4] = f2bf(hn);
    }
    if (t >= TW_ - 1) {
      pp0v += __shfl_xor(pp0v, 16); pp0v += __shfl_xor(pp0v, 32);
      pp1v += __shfl_xor(pp1v, 16); pp1v += __shfl_xor(pp1v, 32);
      if (l4 == 0) {
        sm.l.pp_lds[wave][l16][0] = pp0v;
        sm.l.pp_lds[wave][l16][1] = pp1v;
      }
    }
    __syncthreads();   // S2

    // ---- phase D: coalesced coherent stores ----
    if (tid < 64) {                        // h: 16 rows x 64B, 16B/lane
      int row = tid >> 2, qd = tid & 3;
      u32x4 v = *(const u32x4*)&sm.l.h_out[row][qd*8];
      st16c(hnext + (size_t)(rbase+row)*H_ + hbase + qd*8, v);
      if (t == TW_ - 1)
        *(u32x4*)(warm + (size_t)(rbase+row)*H_ + hbase + qd*8) = v;
    }
    if (t >= TW_ - 1 && tid < 8) {         // pp: 128B contiguous per block
      f32x4 pv;
#pragma unroll
      for (int j = 0; j < 4; j++) {
        int idx = tid*4 + j, row = idx >> 1, c = idx & 1;
        pv[j] = sm.l.pp_lds[0][row][c] + sm.l.pp_lds[1][row][c]
              + sm.l.pp_lds[2][row][c] + sm.l.pp_lds[3][row][c];
      }
      stf16c(ppnext + (size_t)(team*MEMBERS + member)*32 + tid*4, pv);
    }

    // ---- barrier: drain, ONE arrive per block, single poller, release ----
    asm volatile("s_waitcnt vmcnt(0)" ::: "memory");
    __syncthreads();   // S3: every wave's stores at the coherence point
    if (tid == 0) {
      ARRIVE(ctr);
      int need = MEMBERS * (t + 1);
      while (LOAD_CI(ctr) < need) {}
    }
    __syncthreads();   // S4
  }

  // ---- final pred (k=95) from pp of step 190 (pp1 side) ----
  if (member == 0 && tid < 32) {
    int row = tid >> 1, c = tid & 1;
    const float* pps = pp1 + (size_t)team*MEMBERS*32 + row*2 + c;
    float s = c ? bwc1 : bwc0;
#pragma unroll
    for (int m = 0; m < MEMBERS; m++) s += LOAD_CF(pps + m*32);
    out_pred[((size_t)(rbase+row)*96 + 95)*2 + c] = s;
  }
  __builtin_amdgcn_s_setprio(0);
}

// ---------------------------------------------------------------------------
// Post-lstm: GEMM over K in [0,512) — B = warm_out (bf16), A = Wcc[0:512].
// grid 16 x 256. Writes the 9th partial (1MB).
// ---------------------------------------------------------------------------
__global__ __launch_bounds__(256, 1) void gemm0_kernel(
    const unsigned short* __restrict__ warm, const float* __restrict__ Wcc,
    float* __restrict__ partial8)
{
  const int nc = blockIdx.x;
  const int tid = threadIdx.x;
  const int w = tid >> 6, lane = tid & 63;
  const int l4 = lane >> 4, l16 = lane & 15;

  f32x4 zero = {0.f,0.f,0.f,0.f};
  f32x4 acc[16];
#pragma unroll
  for (int i = 0; i < 16; i++) acc[i] = zero;

  const int nrow = nc*64 + w*16 + l16;
  for (int ks = 0; ks < 16; ks++) {
    const float* wp = Wcc + (size_t)(ks*32 + l4*8) * 1024 + nrow;
    short8 af;
#pragma unroll
    for (int j = 0; j < 8; j++) af[j] = (short)f2bf(wp[(size_t)j * 1024]);
    const unsigned short* cp = warm + ks*32 + l4*8;
#pragma unroll
    for (int bt = 0; bt < 16; bt++) {
      short8 bf = *(const short8*)(cp + (size_t)(bt*16 + l16) * 512);
      acc[bt] = __builtin_amdgcn_mfma_f32_16x16x32_bf16(af, bf, acc[bt], 0,0,0);
    }
  }
  float* pp = partial8 + (size_t)(nc*64 + w*16 + l4*4)*256 + l16;
#pragma unroll
  for (int bt = 0; bt < 16; bt++)
#pragma unroll
    for (int r = 0; r < 4; r++)
      pp[(size_t)r*256 + bt*16] = acc[bt][r];
}

// ctT[n][b] = relu(bcc[n] + sum_{p<8} partialT[p][n][b] + partial8[n][b]);
// also copies the inputs-passthrough output.
__global__ void reduce_kernel(const float* __restrict__ partialT,
                              const float* __restrict__ partial8,
                              const float* __restrict__ bcc, float* __restrict__ ctT,
                              const float* __restrict__ inputs, float* __restrict__ out)
{
  int e = blockIdx.x * 256 + threadIdx.x;   // 1024 blocks
  int n = e >> 8;
  float s = bcc[n] + partial8[e];
#pragma unroll
  for (int p = 0; p < 8; p++) s += partialT[(size_t)p*262144 + e];
  ctT[e] = fmaxf(s, 0.f);
  if (e < 65536) out[49920 + e] = inputs[e];
}

// cost/prob heads: one wave per batch row
__global__ void head_kernel(const float* __restrict__ ctT, const float* __restrict__ Wp,
                            const float* __restrict__ bp, const float* __restrict__ Wco,
                            const float* __restrict__ bco, float* __restrict__ out)
{
  int b = blockIdx.x;
  int lane = threadIdx.x;
  float p0 = 0.f, p1 = 0.f, pc = 0.f;
#pragma unroll
  for (int i = 0; i < 16; i++) {
    int n = i*64 + lane;
    float c = ctT[(size_t)n*256 + b];
    p0 += c * Wp[2*n]; p1 += c * Wp[2*n+1]; pc += c * Wco[n];
  }
  for (int m = 1; m < 64; m <<= 1) {
    p0 += __shfl_xor(p0, m); p1 += __shfl_xor(p1, m); pc += __shfl_xor(pc, m);
  }
  if (lane == 0) {
    out[49152 + b]       = pc + bco[0];
    out[49408 + 2*b]     = 1.f / (1.f + __expf(-(p0 + bp[0])));
    out[49408 + 2*b + 1] = 1.f / (1.f + __expf(-(p1 + bp[1])));
  }
}

// ---------------------------------------------------------------------------
extern "C" void kernel_launch(void* const* d_in, const int* in_sizes, int n_in,
                              void* d_out, int out_size, void* d_ws, size_t ws_size,
                              hipStream_t stream) {
  const float* inputs = (const float*)d_in[0];
  const float* Wk   = (const float*)d_in[1];
  const float* Wr   = (const float*)d_in[2];
  const float* bias = (const float*)d_in[3];
  const float* Ww   = (const float*)d_in[4];
  const float* bw   = (const float*)d_in[5];
  const float* Wc   = (const float*)d_in[6];
  const float* bc   = (const float*)d_in[7];
  const float* Wcc  = (const float*)d_in[8];
  const float* bcc  = (const float*)d_in[9];
  const float* Wp   = (const float*)d_in[10];
  const float* bp   = (const float*)d_in[11];
  const float* Wco  = (const float*)d_in[12];
  const float* bco  = (const float*)d_in[13];
  float* out = (float*)d_out;
  char* ws = (char*)d_ws;

  // ws layout (bytes):
  // [0x000000) h0 256KB | [0x040000) flags 8KB | [0x042000) h1 256KB
  // [0x082000) warm 256KB | [0x0C2000) pp0 32KB | [0x0CA000) pp1 32KB |
  // [0x0D2000) partial8 1MB | [0x8C2000) partialT 8MB | [0x10C2000) ctT 1MB
  unsigned short* h0   = (unsigned short*)(ws);
  int*            flags= (int*)(ws + 0x40000);
  unsigned short* h1   = (unsigned short*)(ws + 0x42000);
  unsigned short* warm = (unsigned short*)(ws + 0x82000);
  float*          pp0  = (float*)(ws + 0xC2000);
  float*          pp1  = (float*)(ws + 0xCA000);
  float*          partial8 = (float*)(ws + 0xD2000);
  float*          partialT = (float*)(ws + 0x8C2000);
  float*          ctT  = (float*)(ws + 0x10C2000);

  // zero h0 + flags (re-done every launch; ws not re-poisoned between replays)
  hipMemsetAsync(d_ws, 0, 0x42000, stream);

  mega_kernel<<<512, 256, 0, stream>>>(inputs, Wk, Wr, bias, Ww, bw, Wc, bc, Wcc,
                                       h0, h1, pp0, pp1, warm, flags,
                                       partialT, out);
  gemm0_kernel<<<16, 256, 0, stream>>>(warm, Wcc, partial8);
  reduce_kernel<<<1024, 256, 0, stream>>>(partialT, partial8, bcc, ctT, inputs, out);
  head_kernel<<<256, 64, 0, stream>>>(ctT, Wp, bp, Wco, bco, out);
}

// Round 12
// 713.706 us; speedup vs baseline: 1.1542x; 1.0461x over previous
//
#include <hip/hip_runtime.h>
#include <hip/hip_bf16.h>
#include <stdint.h>

// Problem constants
#define B_    256
#define T_    128
#define W_    32
#define H_    512
#define G4_   2048   // 4*H
#define TW_   96     // warm steps
#define STEPS_ 191   // 96 warm + 95 decode cells
#define TEAMS 16
#define MEMBERS 16
#define ROWS  16     // batch rows per team
#define HC    32     // h-columns per block

typedef __attribute__((ext_vector_type(8))) short short8;
typedef __attribute__((ext_vector_type(4))) float f32x4;
typedef __attribute__((ext_vector_type(4))) uint32_t u32x4;

__device__ __forceinline__ unsigned short f2bf(float f) {
  uint32_t u = __float_as_uint(f);
  u += 0x7fffu + ((u >> 16) & 1u);   // round-to-nearest-even
  return (unsigned short)(u >> 16);
}
__device__ __forceinline__ float sigm(float x) { return 1.f / (1.f + __expf(-x)); }
__device__ __forceinline__ float tanh_(float x) { return 1.f - 2.f / (1.f + __expf(2.f * x)); }

// PROVEN (R6) device-scope primitives: compiler agent atomics for the barrier
// protocol; sc0 sc1 asm (early-clobber outputs) only for bulk data.
#define LOAD_CF(p)      __hip_atomic_load((p), __ATOMIC_RELAXED, __HIP_MEMORY_SCOPE_AGENT)
#define LOAD_CI(p)      __hip_atomic_load((p), __ATOMIC_RELAXED, __HIP_MEMORY_SCOPE_AGENT)
#define ARRIVE(p)       __hip_atomic_fetch_add((p), 1, __ATOMIC_RELAXED, __HIP_MEMORY_SCOPE_AGENT)

__device__ __forceinline__ u32x4 ld16c(const void* p) {
  u32x4 v;
  asm volatile("global_load_dwordx4 %0, %1, off sc0 sc1"
               : "=&v"(v) : "v"(p) : "memory");
  return v;   // caller batches, then s_waitcnt vmcnt(0) + sched_barrier
}
__device__ __forceinline__ void st16c(void* p, u32x4 v) {
  asm volatile("global_store_dwordx4 %0, %1, off sc0 sc1" :: "v"(p), "v"(v) : "memory");
}
__device__ __forceinline__ void stf16c(void* p, f32x4 v) {
  asm volatile("global_store_dwordx4 %0, %1, off sc0 sc1" :: "v"(p), "v"(v) : "memory");
}

// ---------------------------------------------------------------------------
// Persistent LSTM — verbatim R6 structure (532us proven).
// 256 blocks x 256 threads (1/CU). team=blockIdx&15, member=blockIdx>>4.
// ---------------------------------------------------------------------------
__global__ __launch_bounds__(256, 1) void lstm_kernel(
    const float* __restrict__ inputs, const float* __restrict__ Wk,
    const float* __restrict__ Wr, const float* __restrict__ bias,
    const float* __restrict__ Ww, const float* __restrict__ bw,
    unsigned short* __restrict__ h0buf, unsigned short* __restrict__ h1buf,
    float* __restrict__ pp0, float* __restrict__ pp1,
    unsigned short* __restrict__ warm, int* __restrict__ flags,
    float* __restrict__ out_pred)
{
  const int team = blockIdx.x & 15;
  const int member = blockIdx.x >> 4;   // 0..15
  const int rbase = team * ROWS;
  const int hbase = member * HC;
  const int tid = threadIdx.x;
  const int wave = tid >> 6;
  const int lane = tid & 63;
  const int l4 = lane >> 4, l16 = lane & 15;

  __shared__ unsigned short h_lds[ROWS][H_];              // 16KB, XOR swizzled
  __shared__ float x_all[TW_][ROWS][2];                   // 12KB warm inputs
  __shared__ float x_lds[ROWS][2];                        // decode x (pred)
  __shared__ float pp_lds[4][ROWS][2];                    // per-wave partials
  __shared__ alignas(16) unsigned short h_out[ROWS][HC];  // 1KB repack

  for (int i = tid; i < TW_*ROWS*2; i += 256) {
    int tt = i >> 5, row = (i >> 1) & 15, c = i & 1;
    x_all[tt][row][c] = inputs[(size_t)(rbase+row)*(T_*2) + (W_+tt)*2 + c];
  }

  const int gateL = l16 & 3, hclL = l16 >> 2;
  short8 afrag[2][16];          // Wr^T fragments: 128 VGPRs
  float bbv[2][4], wk0v[2][4], wk1v[2][4], wwv[2][2];
#pragma unroll
  for (int a = 0; a < 2; a++) {
    const int gcA = gateL*H_ + hbase + wave*8 + a*4 + hclL;
#pragma unroll
    for (int ks = 0; ks < 16; ks++) {
      const float* wp = Wr + (size_t)(ks*32 + l4*8) * G4_ + gcA;
#pragma unroll
      for (int j = 0; j < 8; j++) afrag[a][ks][j] = (short)f2bf(wp[(size_t)j * G4_]);
    }
    const int colA = hbase + wave*8 + a*4 + l4;
#pragma unroll
    for (int j = 0; j < 4; j++) {
      int gcj = j*H_ + colA;
      bbv[a][j] = bias[gcj]; wk0v[a][j] = Wk[gcj]; wk1v[a][j] = Wk[G4_ + gcj];
    }
    wwv[a][0] = Ww[2*colA]; wwv[a][1] = Ww[2*colA + 1];
  }
  const float bwc0 = bw[0], bwc1 = bw[1];
  float creg[2] = {0.f, 0.f};
  __syncthreads();

  int* ctr = flags + team * 16;                 // 64B-spaced step counter
  const int srow = tid >> 4, sg = tid & 15;     // h-stage: 16 thr/row, 4x16B

  for (int t = 0; t < STEPS_; t++) {
    const unsigned short* hprev = (t & 1) ? h1buf : h0buf;
    unsigned short* hnext = (t & 1) ? h0buf : h1buf;
    const float* ppprev = (t & 1) ? pp1 : pp0;
    float* ppnext = (t & 1) ? pp0 : pp1;

    // ---- phase A: issue ALL coherent loads, one wait, then LDS fill ----
    const bool dox = (t >= TW_) && (tid < 32);
    float vals[MEMBERS];
    if (dox) {
      int row = tid >> 1, c = tid & 1;
      const float* pps = ppprev + (size_t)team*MEMBERS*32 + row*2 + c;
#pragma unroll
      for (int m = 0; m < MEMBERS; m++) vals[m] = LOAD_CF(pps + m*32);
    }
    u32x4 q[4];
    {
      const unsigned short* srcb = hprev + (size_t)(rbase+srow)*H_ + sg*8;
#pragma unroll
      for (int i = 0; i < 4; i++) q[i] = ld16c(srcb + i*128);   // granule sg+16i
    }
    asm volatile("s_waitcnt vmcnt(0)" ::: "memory");
    __builtin_amdgcn_sched_barrier(0);
#pragma unroll
    for (int i = 0; i < 4; i++)
      *(u32x4*)&h_lds[srow][((sg + 16*i) ^ (srow & 7)) * 8] = q[i];
    if (dox) {
      int row = tid >> 1, c = tid & 1;
      float s = c ? bwc1 : bwc0;
#pragma unroll
      for (int m = 0; m < MEMBERS; m++) s += vals[m];
      x_lds[row][c] = s;
      if (member == 0)
        out_pred[((size_t)(rbase+row)*96 + (t - TW_))*2 + c] = s;
    }
    __syncthreads();   // S1

    // ---- phase B: z^T = Wr^T @ h^T (+ bias + Wk*x), MFMA over K=512 ----
    f32x4 acc[2];
    const float* xsrc = (t < TW_) ? &x_all[t][0][0] : &x_lds[0][0];
    {
      float x0 = xsrc[2*l16], x1 = xsrc[2*l16 + 1];
#pragma unroll
      for (int a = 0; a < 2; a++)
#pragma unroll
        for (int j = 0; j < 4; j++)
          acc[a][j] = bbv[a][j] + wk0v[a][j]*x0 + wk1v[a][j]*x1;
    }
#pragma unroll
    for (int ks = 0; ks < 16; ks++) {
      int pg = ((ks*4 + l4) ^ (l16 & 7)) * 8;
      short8 b0 = *(const short8*)&h_lds[l16][pg];
      acc[0] = __builtin_amdgcn_mfma_f32_16x16x32_bf16(afrag[0][ks], b0, acc[0], 0,0,0);
      acc[1] = __builtin_amdgcn_mfma_f32_16x16x32_bf16(afrag[1][ks], b0, acc[1], 0,0,0);
    }

    // ---- phase C: in-register cell update -> h_out + pred partials ----
    float pp0v = 0.f, pp1v = 0.f;
#pragma unroll
    for (int a = 0; a < 2; a++) {
      float zi = acc[a][0], zf = acc[a][1], zg = acc[a][2], zo = acc[a][3];
      float cn = sigm(zf)*creg[a] + sigm(zi)*tanh_(zg);
      float hn = sigm(zo)*tanh_(cn);
      creg[a] = cn;
      pp0v += hn * wwv[a][0];
      pp1v += hn * wwv[a][1];
      h_out[l16][wave*8 + a*4 + l4] = f2bf(hn);
    }
    if (t >= TW_ - 1) {
      pp0v += __shfl_xor(pp0v, 16); pp0v += __shfl_xor(pp0v, 32);
      pp1v += __shfl_xor(pp1v, 16); pp1v += __shfl_xor(pp1v, 32);
      if (l4 == 0) {
        pp_lds[wave][l16][0] = pp0v;
        pp_lds[wave][l16][1] = pp1v;
      }
    }
    __syncthreads();   // S2

    // ---- phase D: coalesced coherent stores ----
    if (tid < 64) {                        // h: 16 rows x 64B, 16B/lane
      int row = tid >> 2, qd = tid & 3;
      u32x4 v = *(const u32x4*)&h_out[row][qd*8];
      st16c(hnext + (size_t)(rbase+row)*H_ + hbase + qd*8, v);
      if (t == TW_ - 1)
        *(u32x4*)(warm + (size_t)(rbase+row)*H_ + hbase + qd*8) = v;
    }
    if (t >= TW_ - 1 && tid < 8) {         // pp: 128B contiguous per block
      f32x4 pv;
#pragma unroll
      for (int j = 0; j < 4; j++) {
        int idx = tid*4 + j, row = idx >> 1, c = idx & 1;
        pv[j] = pp_lds[0][row][c] + pp_lds[1][row][c]
              + pp_lds[2][row][c] + pp_lds[3][row][c];
      }
      stf16c(ppnext + (size_t)(team*MEMBERS + member)*32 + tid*4, pv);
    }

    // ---- barrier: drain, ONE arrive per block, single poller, release ----
    asm volatile("s_waitcnt vmcnt(0)" ::: "memory");
    __syncthreads();   // S3
    if (tid == 0) {
      ARRIVE(ctr);
      int need = MEMBERS * (t + 1);
      while (LOAD_CI(ctr) < need) {}
    }
    __syncthreads();   // S4
  }

  // ---- final pred (k=95) from pp of step 190 (pp1 side) ----
  if (member == 0 && tid < 32) {
    int row = tid >> 1, c = tid & 1;
    const float* pps = pp1 + (size_t)team*MEMBERS*32 + row*2 + c;
    float s = c ? bwc1 : bwc0;
#pragma unroll
    for (int m = 0; m < MEMBERS; m++) s += LOAD_CF(pps + m*32);
    out_pred[((size_t)(rbase+row)*96 + 95)*2 + c] = s;
  }
}

// ---------------------------------------------------------------------------
// Big GEMM, K in [512,16384): on-the-fly B = relu(x@Wc+bc) (proven in R10/11
// mega role). 256 blocks (32 nc x 8 kc), ALL 4 waves active via
// (n-half, b-half) split: wave = (bhalf<<1)|nhalf, 8 bt-tiles each.
// ---------------------------------------------------------------------------
__global__ __launch_bounds__(256, 1) void gemm_kernel(
    const float* __restrict__ inputs, const float* __restrict__ Wc,
    const float* __restrict__ bc, const float* __restrict__ Wcc,
    float* __restrict__ partialT)
{
  __shared__ float wc0[512], wc1[512], bcl[512];
  __shared__ float xin[256][10];

  const int tid = threadIdx.x;
  const int wave = tid >> 6, lane = tid & 63;
  const int l4 = lane >> 4, l16 = lane & 15;
  const int nc = blockIdx.x & 31, kc = blockIdx.x >> 5;   // 32 nc x 8 kc
  const int koff = (kc == 0) ? 0 : kc*2048 - 512;
  const int nks  = (kc == 0) ? 48 : 64;
  const int w0 = koff >> 9;
  const int nw = (kc == 0) ? 3 : 5;

  for (int i = tid; i < 512; i += 256) {
    wc0[i] = Wc[i]; wc1[i] = Wc[512 + i]; bcl[i] = bc[i];
  }
  for (int i = tid; i < 256*nw*2; i += 256) {
    int row = i / (nw*2), r = i - row*(nw*2);
    xin[row][r] = inputs[(size_t)row*(T_*2) + w0*2 + r];
  }
  __syncthreads();

  const int nhalf = wave & 1, bhalf = wave >> 1;
  const int nrow = nc*32 + nhalf*16 + l16;
  f32x4 zero = {0.f,0.f,0.f,0.f};
  f32x4 acc[8];
#pragma unroll
  for (int i = 0; i < 8; i++) acc[i] = zero;

  for (int ks = 0; ks < nks; ks++) {
    const int kkl = koff + ks*32 + l4*8;
    const float* wp = Wcc + (size_t)(512 + kkl) * 1024 + nrow;
    short8 af;
#pragma unroll
    for (int j = 0; j < 8; j++) af[j] = (short)f2bf(wp[(size_t)j * 1024]);
    const int w = kkl >> 9, hc = kkl & 511;
    const int wi = (w - w0)*2;
    float c0[8], c1[8], cb[8];
#pragma unroll
    for (int j = 0; j < 8; j++) {
      c0[j] = wc0[hc+j]; c1[j] = wc1[hc+j]; cb[j] = bcl[hc+j];
    }
#pragma unroll
    for (int bt = 0; bt < 8; bt++) {
      int row = bhalf*128 + bt*16 + l16;
      float x0 = xin[row][wi], x1 = xin[row][wi+1];
      short8 bf;
#pragma unroll
      for (int j = 0; j < 8; j++) {
        float v = fmaf(x0, c0[j], fmaf(x1, c1[j], cb[j]));
        bf[j] = (short)f2bf(fmaxf(v, 0.f));
      }
      acc[bt] = __builtin_amdgcn_mfma_f32_16x16x32_bf16(af, bf, acc[bt], 0,0,0);
    }
  }
  float* pp = partialT + (size_t)kc*262144
            + (size_t)(nc*32 + nhalf*16 + l4*4)*256 + bhalf*128 + l16;
#pragma unroll
  for (int bt = 0; bt < 8; bt++)
#pragma unroll
    for (int r = 0; r < 4; r++)
      pp[(size_t)r*256 + bt*16] = acc[bt][r];
}

// ---------------------------------------------------------------------------
// GEMM over K in [0,512): B = warm_out (bf16), A = Wcc[0:512]. 16 blocks.
// ---------------------------------------------------------------------------
__global__ __launch_bounds__(256, 1) void gemm0_kernel(
    const unsigned short* __restrict__ warm, const float* __restrict__ Wcc,
    float* __restrict__ partial8)
{
  const int nc = blockIdx.x;
  const int tid = threadIdx.x;
  const int w = tid >> 6, lane = tid & 63;
  const int l4 = lane >> 4, l16 = lane & 15;

  f32x4 zero = {0.f,0.f,0.f,0.f};
  f32x4 acc[16];
#pragma unroll
  for (int i = 0; i < 16; i++) acc[i] = zero;

  const int nrow = nc*64 + w*16 + l16;
  for (int ks = 0; ks < 16; ks++) {
    const float* wp = Wcc + (size_t)(ks*32 + l4*8) * 1024 + nrow;
    short8 af;
#pragma unroll
    for (int j = 0; j < 8; j++) af[j] = (short)f2bf(wp[(size_t)j * 1024]);
    const unsigned short* cp = warm + ks*32 + l4*8;
#pragma unroll
    for (int bt = 0; bt < 16; bt++) {
      short8 bf = *(const short8*)(cp + (size_t)(bt*16 + l16) * 512);
      acc[bt] = __builtin_amdgcn_mfma_f32_16x16x32_bf16(af, bf, acc[bt], 0,0,0);
    }
  }
  float* pp = partial8 + (size_t)(nc*64 + w*16 + l4*4)*256 + l16;
#pragma unroll
  for (int bt = 0; bt < 16; bt++)
#pragma unroll
    for (int r = 0; r < 4; r++)
      pp[(size_t)r*256 + bt*16] = acc[bt][r];
}

// ctT[n][b] = relu(bcc[n] + sum_{p<8} partialT[p][n][b] + partial8[n][b]);
// also copies the inputs-passthrough output.
__global__ void reduce_kernel(const float* __restrict__ partialT,
                              const float* __restrict__ partial8,
                              const float* __restrict__ bcc, float* __restrict__ ctT,
                              const float* __restrict__ inputs, float* __restrict__ out)
{
  int e = blockIdx.x * 256 + threadIdx.x;   // 1024 blocks
  int n = e >> 8;
  float s = bcc[n] + partial8[e];
#pragma unroll
  for (int p = 0; p < 8; p++) s += partialT[(size_t)p*262144 + e];
  ctT[e] = fmaxf(s, 0.f);
  if (e < 65536) out[49920 + e] = inputs[e];
}

// cost/prob heads: one wave per batch row
__global__ void head_kernel(const float* __restrict__ ctT, const float* __restrict__ Wp,
                            const float* __restrict__ bp, const float* __restrict__ Wco,
                            const float* __restrict__ bco, float* __restrict__ out)
{
  int b = blockIdx.x;
  int lane = threadIdx.x;
  float p0 = 0.f, p1 = 0.f, pc = 0.f;
#pragma unroll
  for (int i = 0; i < 16; i++) {
    int n = i*64 + lane;
    float c = ctT[(size_t)n*256 + b];
    p0 += c * Wp[2*n]; p1 += c * Wp[2*n+1]; pc += c * Wco[n];
  }
  for (int m = 1; m < 64; m <<= 1) {
    p0 += __shfl_xor(p0, m); p1 += __shfl_xor(p1, m); pc += __shfl_xor(pc, m);
  }
  if (lane == 0) {
    out[49152 + b]       = pc + bco[0];
    out[49408 + 2*b]     = 1.f / (1.f + __expf(-(p0 + bp[0])));
    out[49408 + 2*b + 1] = 1.f / (1.f + __expf(-(p1 + bp[1])));
  }
}

// ---------------------------------------------------------------------------
extern "C" void kernel_launch(void* const* d_in, const int* in_sizes, int n_in,
                              void* d_out, int out_size, void* d_ws, size_t ws_size,
                              hipStream_t stream) {
  const float* inputs = (const float*)d_in[0];
  const float* Wk   = (const float*)d_in[1];
  const float* Wr   = (const float*)d_in[2];
  const float* bias = (const float*)d_in[3];
  const float* Ww   = (const float*)d_in[4];
  const float* bw   = (const float*)d_in[5];
  const float* Wc   = (const float*)d_in[6];
  const float* bc   = (const float*)d_in[7];
  const float* Wcc  = (const float*)d_in[8];
  const float* bcc  = (const float*)d_in[9];
  const float* Wp   = (const float*)d_in[10];
  const float* bp   = (const float*)d_in[11];
  const float* Wco  = (const float*)d_in[12];
  const float* bco  = (const float*)d_in[13];
  float* out = (float*)d_out;
  char* ws = (char*)d_ws;

  // ws layout (bytes):
  // [0x000000) h0 256KB | [0x040000) flags 8KB | [0x042000) h1 256KB
  // [0x082000) warm 256KB | [0x0C2000) pp0 32KB | [0x0CA000) pp1 32KB |
  // [0x0D2000) partial8 1MB | [0x8C2000) partialT 8MB | [0x10C2000) ctT 1MB
  unsigned short* h0   = (unsigned short*)(ws);
  int*            flags= (int*)(ws + 0x40000);
  unsigned short* h1   = (unsigned short*)(ws + 0x42000);
  unsigned short* warm = (unsigned short*)(ws + 0x82000);
  float*          pp0  = (float*)(ws + 0xC2000);
  float*          pp1  = (float*)(ws + 0xCA000);
  float*          partial8 = (float*)(ws + 0xD2000);
  float*          partialT = (float*)(ws + 0x8C2000);
  float*          ctT  = (float*)(ws + 0x10C2000);

  // zero h0 + flags (re-done every launch; ws not re-poisoned between replays)
  hipMemsetAsync(d_ws, 0, 0x42000, stream);

  lstm_kernel<<<TEAMS*MEMBERS, 256, 0, stream>>>(inputs, Wk, Wr, bias, Ww, bw,
                                                 h0, h1, pp0, pp1, warm, flags, out);
  gemm_kernel<<<256, 256, 0, stream>>>(inputs, Wc, bc, Wcc, partialT);
  gemm0_kernel<<<16, 256, 0, stream>>>(warm, Wcc, partial8);
  reduce_kernel<<<1024, 256, 0, stream>>>(partialT, partial8, bcc, ctT, inputs, out);
  head_kernel<<<256, 64, 0, stream>>>(ctT, Wp, bp, Wco, bco, out);
}

// Round 13
// 687.000 us; speedup vs baseline: 1.1991x; 1.0389x over previous
//
#include <hip/hip_runtime.h>
#include <hip/hip_bf16.h>
#include <stdint.h>

// Problem constants
#define B_    256
#define T_    128
#define W_    32
#define H_    512
#define G4_   2048   // 4*H
#define TW_   96     // warm steps
#define STEPS_ 191   // 96 warm + 95 decode cells
#define TEAMS 16
#define MEMBERS 16
#define ROWS  16     // batch rows per team
#define HC    32     // h-columns per block

typedef __attribute__((ext_vector_type(8))) short short8;
typedef __attribute__((ext_vector_type(4))) float f32x4;
typedef __attribute__((ext_vector_type(4))) uint32_t u32x4;

__device__ __forceinline__ unsigned short f2bf(float f) {
  uint32_t u = __float_as_uint(f);
  u += 0x7fffu + ((u >> 16) & 1u);   // round-to-nearest-even
  return (unsigned short)(u >> 16);
}
__device__ __forceinline__ float sigm(float x) { return 1.f / (1.f + __expf(-x)); }
__device__ __forceinline__ float tanh_(float x) { return 1.f - 2.f / (1.f + __expf(2.f * x)); }

// PROVEN (R6) device-scope primitives: compiler agent atomics for the barrier
// protocol; sc0 sc1 asm (early-clobber outputs) only for bulk data.
#define LOAD_CF(p)      __hip_atomic_load((p), __ATOMIC_RELAXED, __HIP_MEMORY_SCOPE_AGENT)
#define LOAD_CI(p)      __hip_atomic_load((p), __ATOMIC_RELAXED, __HIP_MEMORY_SCOPE_AGENT)
#define ARRIVE(p)       __hip_atomic_fetch_add((p), 1, __ATOMIC_RELAXED, __HIP_MEMORY_SCOPE_AGENT)

__device__ __forceinline__ u32x4 ld16c(const void* p) {
  u32x4 v;
  asm volatile("global_load_dwordx4 %0, %1, off sc0 sc1"
               : "=&v"(v) : "v"(p) : "memory");
  return v;   // caller batches, then s_waitcnt vmcnt(0) + sched_barrier
}
__device__ __forceinline__ void st16c(void* p, u32x4 v) {
  asm volatile("global_store_dwordx4 %0, %1, off sc0 sc1" :: "v"(p), "v"(v) : "memory");
}
__device__ __forceinline__ void stf16c(void* p, f32x4 v) {
  asm volatile("global_store_dwordx4 %0, %1, off sc0 sc1" :: "v"(p), "v"(v) : "memory");
}

// ---------------------------------------------------------------------------
// Persistent LSTM — verbatim R6 structure (proven).
// 256 blocks x 256 threads (1/CU). team=blockIdx&15, member=blockIdx>>4.
// ---------------------------------------------------------------------------
__global__ __launch_bounds__(256, 1) void lstm_kernel(
    const float* __restrict__ inputs, const float* __restrict__ Wk,
    const float* __restrict__ Wr, const float* __restrict__ bias,
    const float* __restrict__ Ww, const float* __restrict__ bw,
    unsigned short* __restrict__ h0buf, unsigned short* __restrict__ h1buf,
    float* __restrict__ pp0, float* __restrict__ pp1,
    unsigned short* __restrict__ warm, int* __restrict__ flags,
    float* __restrict__ out_pred)
{
  const int team = blockIdx.x & 15;
  const int member = blockIdx.x >> 4;   // 0..15
  const int rbase = team * ROWS;
  const int hbase = member * HC;
  const int tid = threadIdx.x;
  const int wave = tid >> 6;
  const int lane = tid & 63;
  const int l4 = lane >> 4, l16 = lane & 15;

  __shared__ unsigned short h_lds[ROWS][H_];              // 16KB, XOR swizzled
  __shared__ float x_all[TW_][ROWS][2];                   // 12KB warm inputs
  __shared__ float x_lds[ROWS][2];                        // decode x (pred)
  __shared__ float pp_lds[4][ROWS][2];                    // per-wave partials
  __shared__ alignas(16) unsigned short h_out[ROWS][HC];  // 1KB repack

  for (int i = tid; i < TW_*ROWS*2; i += 256) {
    int tt = i >> 5, row = (i >> 1) & 15, c = i & 1;
    x_all[tt][row][c] = inputs[(size_t)(rbase+row)*(T_*2) + (W_+tt)*2 + c];
  }

  const int gateL = l16 & 3, hclL = l16 >> 2;
  short8 afrag[2][16];          // Wr^T fragments: 128 VGPRs
  float bbv[2][4], wk0v[2][4], wk1v[2][4], wwv[2][2];
#pragma unroll
  for (int a = 0; a < 2; a++) {
    const int gcA = gateL*H_ + hbase + wave*8 + a*4 + hclL;
#pragma unroll
    for (int ks = 0; ks < 16; ks++) {
      const float* wp = Wr + (size_t)(ks*32 + l4*8) * G4_ + gcA;
#pragma unroll
      for (int j = 0; j < 8; j++) afrag[a][ks][j] = (short)f2bf(wp[(size_t)j * G4_]);
    }
    const int colA = hbase + wave*8 + a*4 + l4;
#pragma unroll
    for (int j = 0; j < 4; j++) {
      int gcj = j*H_ + colA;
      bbv[a][j] = bias[gcj]; wk0v[a][j] = Wk[gcj]; wk1v[a][j] = Wk[G4_ + gcj];
    }
    wwv[a][0] = Ww[2*colA]; wwv[a][1] = Ww[2*colA + 1];
  }
  const float bwc0 = bw[0], bwc1 = bw[1];
  float creg[2] = {0.f, 0.f};
  __syncthreads();

  int* ctr = flags + team * 16;                 // 64B-spaced step counter
  const int srow = tid >> 4, sg = tid & 15;     // h-stage: 16 thr/row, 4x16B

  for (int t = 0; t < STEPS_; t++) {
    const unsigned short* hprev = (t & 1) ? h1buf : h0buf;
    unsigned short* hnext = (t & 1) ? h0buf : h1buf;
    const float* ppprev = (t & 1) ? pp1 : pp0;
    float* ppnext = (t & 1) ? pp0 : pp1;

    // ---- phase A: issue ALL coherent loads, one wait, then LDS fill ----
    const bool dox = (t >= TW_) && (tid < 32);
    float vals[MEMBERS];
    if (dox) {
      int row = tid >> 1, c = tid & 1;
      const float* pps = ppprev + (size_t)team*MEMBERS*32 + row*2 + c;
#pragma unroll
      for (int m = 0; m < MEMBERS; m++) vals[m] = LOAD_CF(pps + m*32);
    }
    u32x4 q[4];
    {
      const unsigned short* srcb = hprev + (size_t)(rbase+srow)*H_ + sg*8;
#pragma unroll
      for (int i = 0; i < 4; i++) q[i] = ld16c(srcb + i*128);   // granule sg+16i
    }
    asm volatile("s_waitcnt vmcnt(0)" ::: "memory");
    __builtin_amdgcn_sched_barrier(0);
#pragma unroll
    for (int i = 0; i < 4; i++)
      *(u32x4*)&h_lds[srow][((sg + 16*i) ^ (srow & 7)) * 8] = q[i];
    if (dox) {
      int row = tid >> 1, c = tid & 1;
      float s = c ? bwc1 : bwc0;
#pragma unroll
      for (int m = 0; m < MEMBERS; m++) s += vals[m];
      x_lds[row][c] = s;
      if (member == 0)
        out_pred[((size_t)(rbase+row)*96 + (t - TW_))*2 + c] = s;
    }
    __syncthreads();   // S1

    // ---- phase B: z^T = Wr^T @ h^T (+ bias + Wk*x), MFMA over K=512 ----
    f32x4 acc[2];
    const float* xsrc = (t < TW_) ? &x_all[t][0][0] : &x_lds[0][0];
    {
      float x0 = xsrc[2*l16], x1 = xsrc[2*l16 + 1];
#pragma unroll
      for (int a = 0; a < 2; a++)
#pragma unroll
        for (int j = 0; j < 4; j++)
          acc[a][j] = bbv[a][j] + wk0v[a][j]*x0 + wk1v[a][j]*x1;
    }
#pragma unroll
    for (int ks = 0; ks < 16; ks++) {
      int pg = ((ks*4 + l4) ^ (l16 & 7)) * 8;
      short8 b0 = *(const short8*)&h_lds[l16][pg];
      acc[0] = __builtin_amdgcn_mfma_f32_16x16x32_bf16(afrag[0][ks], b0, acc[0], 0,0,0);
      acc[1] = __builtin_amdgcn_mfma_f32_16x16x32_bf16(afrag[1][ks], b0, acc[1], 0,0,0);
    }

    // ---- phase C: in-register cell update -> h_out + pred partials ----
    float pp0v = 0.f, pp1v = 0.f;
#pragma unroll
    for (int a = 0; a < 2; a++) {
      float zi = acc[a][0], zf = acc[a][1], zg = acc[a][2], zo = acc[a][3];
      float cn = sigm(zf)*creg[a] + sigm(zi)*tanh_(zg);
      float hn = sigm(zo)*tanh_(cn);
      creg[a] = cn;
      pp0v += hn * wwv[a][0];
      pp1v += hn * wwv[a][1];
      h_out[l16][wave*8 + a*4 + l4] = f2bf(hn);
    }
    if (t >= TW_ - 1) {
      pp0v += __shfl_xor(pp0v, 16); pp0v += __shfl_xor(pp0v, 32);
      pp1v += __shfl_xor(pp1v, 16); pp1v += __shfl_xor(pp1v, 32);
      if (l4 == 0) {
        pp_lds[wave][l16][0] = pp0v;
        pp_lds[wave][l16][1] = pp1v;
      }
    }
    __syncthreads();   // S2

    // ---- phase D: coalesced coherent stores ----
    if (tid < 64) {                        // h: 16 rows x 64B, 16B/lane
      int row = tid >> 2, qd = tid & 3;
      u32x4 v = *(const u32x4*)&h_out[row][qd*8];
      st16c(hnext + (size_t)(rbase+row)*H_ + hbase + qd*8, v);
      if (t == TW_ - 1)
        *(u32x4*)(warm + (size_t)(rbase+row)*H_ + hbase + qd*8) = v;
    }
    if (t >= TW_ - 1 && tid < 8) {         // pp: 128B contiguous per block
      f32x4 pv;
#pragma unroll
      for (int j = 0; j < 4; j++) {
        int idx = tid*4 + j, row = idx >> 1, c = idx & 1;
        pv[j] = pp_lds[0][row][c] + pp_lds[1][row][c]
              + pp_lds[2][row][c] + pp_lds[3][row][c];
      }
      stf16c(ppnext + (size_t)(team*MEMBERS + member)*32 + tid*4, pv);
    }

    // ---- barrier: drain, ONE arrive per block, single poller, release ----
    asm volatile("s_waitcnt vmcnt(0)" ::: "memory");
    __syncthreads();   // S3
    if (tid == 0) {
      ARRIVE(ctr);
      int need = MEMBERS * (t + 1);
      while (LOAD_CI(ctr) < need) {}
    }
    __syncthreads();   // S4
  }

  // ---- final pred (k=95) from pp of step 190 (pp1 side) ----
  if (member == 0 && tid < 32) {
    int row = tid >> 1, c = tid & 1;
    const float* pps = pp1 + (size_t)team*MEMBERS*32 + row*2 + c;
    float s = c ? bwc1 : bwc0;
#pragma unroll
    for (int m = 0; m < MEMBERS; m++) s += LOAD_CF(pps + m*32);
    out_pred[((size_t)(rbase+row)*96 + 95)*2 + c] = s;
  }
}

// ---------------------------------------------------------------------------
// Big GEMM, K in [512,16384): on-the-fly B = relu(x@Wc+bc).
// 512 blocks = 8 kc x 32 nc x 2 rh (row halves) -> 2 blocks/CU.
// Explicit af double-buffer: iter k+1's 8 Wcc loads issue before iter k's
// B-build+MFMA, so HBM latency hides under ~500cy of independent VALU.
// ---------------------------------------------------------------------------
__global__ __launch_bounds__(256, 1) void gemm_kernel(
    const float* __restrict__ inputs, const float* __restrict__ Wc,
    const float* __restrict__ bc, const float* __restrict__ Wcc,
    float* __restrict__ partialT)
{
  __shared__ float wc0[512], wc1[512], bcl[512];
  __shared__ float xin[128][10];

  const int tid = threadIdx.x;
  const int wave = tid >> 6, lane = tid & 63;
  const int l4 = lane >> 4, l16 = lane & 15;
  const int rh = blockIdx.x & 1;             // row half: 128 rows
  const int nc = (blockIdx.x >> 1) & 31;     // 32 n-chunks of 32
  const int kc = blockIdx.x >> 6;            // 8 k-chunks
  const int koff = (kc == 0) ? 0 : kc*2048 - 512;   // kk = k-512 base
  const int nks  = (kc == 0) ? 48 : 64;
  const int w0 = koff >> 9;
  const int nw = (kc == 0) ? 3 : 5;
  const int rbase = rh * 128;

  for (int i = tid; i < 512; i += 256) {
    wc0[i] = Wc[i]; wc1[i] = Wc[512 + i]; bcl[i] = bc[i];
  }
  for (int i = tid; i < 128*nw*2; i += 256) {
    int row = i / (nw*2), r = i - row*(nw*2);
    xin[row][r] = inputs[(size_t)(rbase+row)*(T_*2) + w0*2 + r];
  }
  __syncthreads();

  const int nhalf = wave & 1, bq = wave >> 1;   // bq: 64-row quarter
  const int nrow = nc*32 + nhalf*16 + l16;
  f32x4 zero = {0.f,0.f,0.f,0.f};
  f32x4 acc[4];
#pragma unroll
  for (int i = 0; i < 4; i++) acc[i] = zero;

  float fa[8], fn[8];
  {
    const float* wp = Wcc + (size_t)(512 + koff + l4*8) * 1024 + nrow;
#pragma unroll
    for (int j = 0; j < 8; j++) fa[j] = wp[(size_t)j * 1024];
  }
  for (int ks = 0; ks < nks; ks++) {
    const int kkl = koff + ks*32 + l4*8;
    if (ks + 1 < nks) {
      const float* wp = Wcc + (size_t)(512 + kkl + 32) * 1024 + nrow;
#pragma unroll
      for (int j = 0; j < 8; j++) fn[j] = wp[(size_t)j * 1024];
    }
    short8 af;
#pragma unroll
    for (int j = 0; j < 8; j++) af[j] = (short)f2bf(fa[j]);
    const int w = kkl >> 9, hc = kkl & 511;
    const int wi = (w - w0)*2;
    float c0[8], c1[8], cb[8];
#pragma unroll
    for (int j = 0; j < 8; j++) {
      c0[j] = wc0[hc+j]; c1[j] = wc1[hc+j]; cb[j] = bcl[hc+j];
    }
#pragma unroll
    for (int bt = 0; bt < 4; bt++) {
      int row = bq*64 + bt*16 + l16;
      float x0 = xin[row][wi], x1 = xin[row][wi+1];
      short8 bf;
#pragma unroll
      for (int j = 0; j < 8; j++) {
        float v = fmaf(x0, c0[j], fmaf(x1, c1[j], cb[j]));
        bf[j] = (short)f2bf(fmaxf(v, 0.f));
      }
      acc[bt] = __builtin_amdgcn_mfma_f32_16x16x32_bf16(af, bf, acc[bt], 0,0,0);
    }
#pragma unroll
    for (int j = 0; j < 8; j++) fa[j] = fn[j];
  }
  float* pp = partialT + (size_t)kc*262144
            + (size_t)(nc*32 + nhalf*16 + l4*4)*256 + rbase + bq*64 + l16;
#pragma unroll
  for (int bt = 0; bt < 4; bt++)
#pragma unroll
    for (int r = 0; r < 4; r++)
      pp[(size_t)r*256 + bt*16] = acc[bt][r];
}

// ---------------------------------------------------------------------------
// GEMM over K in [0,512): B = warm_out (bf16), A = Wcc[0:512]. 16 blocks.
// ---------------------------------------------------------------------------
__global__ __launch_bounds__(256, 1) void gemm0_kernel(
    const unsigned short* __restrict__ warm, const float* __restrict__ Wcc,
    float* __restrict__ partial8)
{
  const int nc = blockIdx.x;
  const int tid = threadIdx.x;
  const int w = tid >> 6, lane = tid & 63;
  const int l4 = lane >> 4, l16 = lane & 15;

  f32x4 zero = {0.f,0.f,0.f,0.f};
  f32x4 acc[16];
#pragma unroll
  for (int i = 0; i < 16; i++) acc[i] = zero;

  const int nrow = nc*64 + w*16 + l16;
  for (int ks = 0; ks < 16; ks++) {
    const float* wp = Wcc + (size_t)(ks*32 + l4*8) * 1024 + nrow;
    short8 af;
#pragma unroll
    for (int j = 0; j < 8; j++) af[j] = (short)f2bf(wp[(size_t)j * 1024]);
    const unsigned short* cp = warm + ks*32 + l4*8;
#pragma unroll
    for (int bt = 0; bt < 16; bt++) {
      short8 bf = *(const short8*)(cp + (size_t)(bt*16 + l16) * 512);
      acc[bt] = __builtin_amdgcn_mfma_f32_16x16x32_bf16(af, bf, acc[bt], 0,0,0);
    }
  }
  float* pp = partial8 + (size_t)(nc*64 + w*16 + l4*4)*256 + l16;
#pragma unroll
  for (int bt = 0; bt < 16; bt++)
#pragma unroll
    for (int r = 0; r < 4; r++)
      pp[(size_t)r*256 + bt*16] = acc[bt][r];
}

// ctT[n][b] = relu(bcc[n] + sum_{p<8} partialT[p][n][b] + partial8[n][b]);
// also copies the inputs-passthrough output.
__global__ void reduce_kernel(const float* __restrict__ partialT,
                              const float* __restrict__ partial8,
                              const float* __restrict__ bcc, float* __restrict__ ctT,
                              const float* __restrict__ inputs, float* __restrict__ out)
{
  int e = blockIdx.x * 256 + threadIdx.x;   // 1024 blocks
  int n = e >> 8;
  float s = bcc[n] + partial8[e];
#pragma unroll
  for (int p = 0; p < 8; p++) s += partialT[(size_t)p*262144 + e];
  ctT[e] = fmaxf(s, 0.f);
  if (e < 65536) out[49920 + e] = inputs[e];
}

// cost/prob heads: one wave per batch row
__global__ void head_kernel(const float* __restrict__ ctT, const float* __restrict__ Wp,
                            const float* __restrict__ bp, const float* __restrict__ Wco,
                            const float* __restrict__ bco, float* __restrict__ out)
{
  int b = blockIdx.x;
  int lane = threadIdx.x;
  float p0 = 0.f, p1 = 0.f, pc = 0.f;
#pragma unroll
  for (int i = 0; i < 16; i++) {
    int n = i*64 + lane;
    float c = ctT[(size_t)n*256 + b];
    p0 += c * Wp[2*n]; p1 += c * Wp[2*n+1]; pc += c * Wco[n];
  }
  for (int m = 1; m < 64; m <<= 1) {
    p0 += __shfl_xor(p0, m); p1 += __shfl_xor(p1, m); pc += __shfl_xor(pc, m);
  }
  if (lane == 0) {
    out[49152 + b]       = pc + bco[0];
    out[49408 + 2*b]     = 1.f / (1.f + __expf(-(p0 + bp[0])));
    out[49408 + 2*b + 1] = 1.f / (1.f + __expf(-(p1 + bp[1])));
  }
}

// ---------------------------------------------------------------------------
extern "C" void kernel_launch(void* const* d_in, const int* in_sizes, int n_in,
                              void* d_out, int out_size, void* d_ws, size_t ws_size,
                              hipStream_t stream) {
  const float* inputs = (const float*)d_in[0];
  const float* Wk   = (const float*)d_in[1];
  const float* Wr   = (const float*)d_in[2];
  const float* bias = (const float*)d_in[3];
  const float* Ww   = (const float*)d_in[4];
  const float* bw   = (const float*)d_in[5];
  const float* Wc   = (const float*)d_in[6];
  const float* bc   = (const float*)d_in[7];
  const float* Wcc  = (const float*)d_in[8];
  const float* bcc  = (const float*)d_in[9];
  const float* Wp   = (const float*)d_in[10];
  const float* bp   = (const float*)d_in[11];
  const float* Wco  = (const float*)d_in[12];
  const float* bco  = (const float*)d_in[13];
  float* out = (float*)d_out;
  char* ws = (char*)d_ws;

  // ws layout (bytes):
  // [0x000000) h0 256KB | [0x040000) flags 8KB | [0x042000) h1 256KB
  // [0x082000) warm 256KB | [0x0C2000) pp0 32KB | [0x0CA000) pp1 32KB |
  // [0x0D2000) partial8 1MB | [0x8C2000) partialT 8MB | [0x10C2000) ctT 1MB
  unsigned short* h0   = (unsigned short*)(ws);
  int*            flags= (int*)(ws + 0x40000);
  unsigned short* h1   = (unsigned short*)(ws + 0x42000);
  unsigned short* warm = (unsigned short*)(ws + 0x82000);
  float*          pp0  = (float*)(ws + 0xC2000);
  float*          pp1  = (float*)(ws + 0xCA000);
  float*          partial8 = (float*)(ws + 0xD2000);
  float*          partialT = (float*)(ws + 0x8C2000);
  float*          ctT  = (float*)(ws + 0x10C2000);

  // zero h0 + flags (re-done every launch; ws not re-poisoned between replays)
  hipMemsetAsync(d_ws, 0, 0x42000, stream);

  lstm_kernel<<<TEAMS*MEMBERS, 256, 0, stream>>>(inputs, Wk, Wr, bias, Ww, bw,
                                                 h0, h1, pp0, pp1, warm, flags, out);
  gemm_kernel<<<512, 256, 0, stream>>>(inputs, Wc, bc, Wcc, partialT);
  gemm0_kernel<<<16, 256, 0, stream>>>(warm, Wcc, partial8);
  reduce_kernel<<<1024, 256, 0, stream>>>(partialT, partial8, bcc, ctT, inputs, out);
  head_kernel<<<256, 64, 0, stream>>>(ctT, Wp, bp, Wco, bco, out);
}

// Round 14
// 652.924 us; speedup vs baseline: 1.2617x; 1.0522x over previous
//
#include <hip/hip_runtime.h>
#include <hip/hip_bf16.h>
#include <stdint.h>

// Problem constants
#define B_    256
#define T_    128
#define W_    32
#define H_    512
#define G4_   2048   // 4*H
#define TW_   96     // warm steps
#define STEPS_ 191   // 96 warm + 95 decode cells
#define TEAMS 16
#define MEMBERS 16
#define ROWS  16     // batch rows per team
#define HC    32     // h-columns per block

typedef __attribute__((ext_vector_type(8))) short short8;
typedef __attribute__((ext_vector_type(4))) float f32x4;
typedef __attribute__((ext_vector_type(4))) uint32_t u32x4;

__device__ __forceinline__ unsigned short f2bf(float f) {
  uint32_t u = __float_as_uint(f);
  u += 0x7fffu + ((u >> 16) & 1u);   // round-to-nearest-even
  return (unsigned short)(u >> 16);
}
__device__ __forceinline__ float sigm(float x) { return 1.f / (1.f + __expf(-x)); }
__device__ __forceinline__ float tanh_(float x) { return 1.f - 2.f / (1.f + __expf(2.f * x)); }

// PROVEN (R6) device-scope primitives: compiler agent atomics for the barrier
// protocol; sc0 sc1 asm (early-clobber outputs) only for bulk data.
#define LOAD_CF(p)      __hip_atomic_load((p), __ATOMIC_RELAXED, __HIP_MEMORY_SCOPE_AGENT)
#define LOAD_CI(p)      __hip_atomic_load((p), __ATOMIC_RELAXED, __HIP_MEMORY_SCOPE_AGENT)
#define ARRIVE(p)       __hip_atomic_fetch_add((p), 1, __ATOMIC_RELAXED, __HIP_MEMORY_SCOPE_AGENT)

__device__ __forceinline__ u32x4 ld16c(const void* p) {
  u32x4 v;
  asm volatile("global_load_dwordx4 %0, %1, off sc0 sc1"
               : "=&v"(v) : "v"(p) : "memory");
  return v;   // caller batches, then s_waitcnt vmcnt(0) + sched_barrier
}
__device__ __forceinline__ void st16c(void* p, u32x4 v) {
  asm volatile("global_store_dwordx4 %0, %1, off sc0 sc1" :: "v"(p), "v"(v) : "memory");
}
__device__ __forceinline__ void stf16c(void* p, f32x4 v) {
  asm volatile("global_store_dwordx4 %0, %1, off sc0 sc1" :: "v"(p), "v"(v) : "memory");
}

// ---------------------------------------------------------------------------
// Persistent LSTM (verbatim R6/R13 protocol) + GEMM-in-barrier-shadow.
// 256 blocks x 256 threads. lstm: team=blockIdx&15, member=blockIdx>>4.
// gemm: kc=blockIdx>>5 (8 k-chunks), gnc=blockIdx&31 (32 n-chunks).
// Every 3rd step, after ARRIVE and before the poll, all waves run ONE GEMM
// k-iteration (prefetched 3 steps ahead) — filling the barrier-wait shadow.
// ---------------------------------------------------------------------------
__global__ __launch_bounds__(256, 1) void lstm_kernel(
    const float* __restrict__ inputs, const float* __restrict__ Wk,
    const float* __restrict__ Wr, const float* __restrict__ bias,
    const float* __restrict__ Ww, const float* __restrict__ bw,
    const float* __restrict__ Wc, const float* __restrict__ bc,
    const float* __restrict__ Wcc,
    unsigned short* __restrict__ h0buf, unsigned short* __restrict__ h1buf,
    float* __restrict__ pp0, float* __restrict__ pp1,
    unsigned short* __restrict__ warm, int* __restrict__ flags,
    float* __restrict__ partialT, float* __restrict__ out_pred)
{
  const int team = blockIdx.x & 15;
  const int member = blockIdx.x >> 4;   // 0..15
  const int rbase = team * ROWS;
  const int hbase = member * HC;
  const int tid = threadIdx.x;
  const int wave = tid >> 6;
  const int lane = tid & 63;
  const int l4 = lane >> 4, l16 = lane & 15;

  __shared__ unsigned short h_lds[ROWS][H_];              // 16KB, XOR swizzled
  __shared__ float x_all[TW_][ROWS][2];                   // 12KB warm inputs
  __shared__ float x_lds[ROWS][2];                        // decode x (pred)
  __shared__ float pp_lds[4][ROWS][2];                    // per-wave partials
  __shared__ alignas(16) unsigned short h_out[ROWS][HC];  // 1KB repack
  __shared__ float wc0[512], wc1[512], bcl[512];          // 6KB gemm tables
  __shared__ float xin[256][10];                          // 10KB gemm x pairs

  // ---- gemm slice for this block ----
  const int kc = blockIdx.x >> 5, gnc = blockIdx.x & 31;
  const int koff = (kc == 0) ? 0 : kc*2048 - 512;
  const int nks  = (kc == 0) ? 48 : 64;
  const int gw0 = koff >> 9;

  for (int i = tid; i < TW_*ROWS*2; i += 256) {
    int tt = i >> 5, row = (i >> 1) & 15, c = i & 1;
    x_all[tt][row][c] = inputs[(size_t)(rbase+row)*(T_*2) + (W_+tt)*2 + c];
  }
  for (int i = tid; i < 512; i += 256) {
    wc0[i] = Wc[i]; wc1[i] = Wc[512 + i]; bcl[i] = bc[i];
  }
  for (int i = tid; i < 2560; i += 256) {
    int row = i / 10, r = i - row*10;
    xin[row][r] = inputs[(size_t)row*(T_*2) + gw0*2 + r];
  }

  const int gateL = l16 & 3, hclL = l16 >> 2;
  short8 afrag[2][16];          // Wr^T fragments: 128 VGPRs
  float bbv[2][4], wk0v[2][4], wk1v[2][4], wwv[2][2];
#pragma unroll
  for (int a = 0; a < 2; a++) {
    const int gcA = gateL*H_ + hbase + wave*8 + a*4 + hclL;
#pragma unroll
    for (int ks = 0; ks < 16; ks++) {
      const float* wp = Wr + (size_t)(ks*32 + l4*8) * G4_ + gcA;
#pragma unroll
      for (int j = 0; j < 8; j++) afrag[a][ks][j] = (short)f2bf(wp[(size_t)j * G4_]);
    }
    const int colA = hbase + wave*8 + a*4 + l4;
#pragma unroll
    for (int j = 0; j < 4; j++) {
      int gcj = j*H_ + colA;
      bbv[a][j] = bias[gcj]; wk0v[a][j] = Wk[gcj]; wk1v[a][j] = Wk[G4_ + gcj];
    }
    wwv[a][0] = Ww[2*colA]; wwv[a][1] = Ww[2*colA + 1];
  }
  const float bwc0 = bw[0], bwc1 = bw[1];
  float creg[2] = {0.f, 0.f};

  // ---- gemm per-wave state + initial prefetch (q=0) ----
  const int nhalf = wave & 1, bhalf = wave >> 1;
  const int gnrow = gnc*32 + nhalf*16 + l16;
  f32x4 gacc[8];
#pragma unroll
  for (int i = 0; i < 8; i++) gacc[i] = (f32x4){0.f,0.f,0.f,0.f};
  float fn[8];
  {
    const float* wp = Wcc + (size_t)(512 + koff + l4*8) * 1024 + gnrow;
#pragma unroll
    for (int j = 0; j < 8; j++) fn[j] = wp[(size_t)j * 1024];
  }
  int gq = 0, gphase = 0;
  __syncthreads();

  int* ctr = flags + team * 16;                 // 64B-spaced step counter
  const int srow = tid >> 4, sg = tid & 15;     // h-stage: 16 thr/row, 4x16B

  for (int t = 0; t < STEPS_; t++) {
    const unsigned short* hprev = (t & 1) ? h1buf : h0buf;
    unsigned short* hnext = (t & 1) ? h0buf : h1buf;
    const float* ppprev = (t & 1) ? pp1 : pp0;
    float* ppnext = (t & 1) ? pp0 : pp1;

    // ---- phase A: issue ALL coherent loads, one wait, then LDS fill ----
    const bool dox = (t >= TW_) && (tid < 32);
    float vals[MEMBERS];
    if (dox) {
      int row = tid >> 1, c = tid & 1;
      const float* pps = ppprev + (size_t)team*MEMBERS*32 + row*2 + c;
#pragma unroll
      for (int m = 0; m < MEMBERS; m++) vals[m] = LOAD_CF(pps + m*32);
    }
    u32x4 q[4];
    {
      const unsigned short* srcb = hprev + (size_t)(rbase+srow)*H_ + sg*8;
#pragma unroll
      for (int i = 0; i < 4; i++) q[i] = ld16c(srcb + i*128);   // granule sg+16i
    }
    asm volatile("s_waitcnt vmcnt(0)" ::: "memory");
    __builtin_amdgcn_sched_barrier(0);
#pragma unroll
    for (int i = 0; i < 4; i++)
      *(u32x4*)&h_lds[srow][((sg + 16*i) ^ (srow & 7)) * 8] = q[i];
    if (dox) {
      int row = tid >> 1, c = tid & 1;
      float s = c ? bwc1 : bwc0;
#pragma unroll
      for (int m = 0; m < MEMBERS; m++) s += vals[m];
      x_lds[row][c] = s;
      if (member == 0)
        out_pred[((size_t)(rbase+row)*96 + (t - TW_))*2 + c] = s;
    }
    __syncthreads();   // S1

    // ---- phase B: z^T = Wr^T @ h^T (+ bias + Wk*x), MFMA over K=512 ----
    f32x4 acc[2];
    const float* xsrc = (t < TW_) ? &x_all[t][0][0] : &x_lds[0][0];
    {
      float x0 = xsrc[2*l16], x1 = xsrc[2*l16 + 1];
#pragma unroll
      for (int a = 0; a < 2; a++)
#pragma unroll
        for (int j = 0; j < 4; j++)
          acc[a][j] = bbv[a][j] + wk0v[a][j]*x0 + wk1v[a][j]*x1;
    }
#pragma unroll
    for (int ks = 0; ks < 16; ks++) {
      int pg = ((ks*4 + l4) ^ (l16 & 7)) * 8;
      short8 b0 = *(const short8*)&h_lds[l16][pg];
      acc[0] = __builtin_amdgcn_mfma_f32_16x16x32_bf16(afrag[0][ks], b0, acc[0], 0,0,0);
      acc[1] = __builtin_amdgcn_mfma_f32_16x16x32_bf16(afrag[1][ks], b0, acc[1], 0,0,0);
    }

    // ---- phase C: in-register cell update -> h_out + pred partials ----
    float pp0v = 0.f, pp1v = 0.f;
#pragma unroll
    for (int a = 0; a < 2; a++) {
      float zi = acc[a][0], zf = acc[a][1], zg = acc[a][2], zo = acc[a][3];
      float cn = sigm(zf)*creg[a] + sigm(zi)*tanh_(zg);
      float hn = sigm(zo)*tanh_(cn);
      creg[a] = cn;
      pp0v += hn * wwv[a][0];
      pp1v += hn * wwv[a][1];
      h_out[l16][wave*8 + a*4 + l4] = f2bf(hn);
    }
    if (t >= TW_ - 1) {
      pp0v += __shfl_xor(pp0v, 16); pp0v += __shfl_xor(pp0v, 32);
      pp1v += __shfl_xor(pp1v, 16); pp1v += __shfl_xor(pp1v, 32);
      if (l4 == 0) {
        pp_lds[wave][l16][0] = pp0v;
        pp_lds[wave][l16][1] = pp1v;
      }
    }
    __syncthreads();   // S2

    // ---- phase D: coalesced coherent stores ----
    if (tid < 64) {                        // h: 16 rows x 64B, 16B/lane
      int row = tid >> 2, qd = tid & 3;
      u32x4 v = *(const u32x4*)&h_out[row][qd*8];
      st16c(hnext + (size_t)(rbase+row)*H_ + hbase + qd*8, v);
      if (t == TW_ - 1)
        *(u32x4*)(warm + (size_t)(rbase+row)*H_ + hbase + qd*8) = v;
    }
    if (t >= TW_ - 1 && tid < 8) {         // pp: 128B contiguous per block
      f32x4 pv;
#pragma unroll
      for (int j = 0; j < 4; j++) {
        int idx = tid*4 + j, row = idx >> 1, c = idx & 1;
        pv[j] = pp_lds[0][row][c] + pp_lds[1][row][c]
              + pp_lds[2][row][c] + pp_lds[3][row][c];
      }
      stf16c(ppnext + (size_t)(team*MEMBERS + member)*32 + tid*4, pv);
    }

    // ---- barrier: drain, arrive, GEMM quantum in the wait shadow, poll ----
    asm volatile("s_waitcnt vmcnt(0)" ::: "memory");
    __syncthreads();   // S3: every wave's stores at the coherence point
    if (tid == 0) ARRIVE(ctr);

    if (gphase == 0 && gq < nks) {         // one GEMM k-iteration
      const int kkl = koff + gq*32 + l4*8;
      short8 af;
#pragma unroll
      for (int j = 0; j < 8; j++) af[j] = (short)f2bf(fn[j]);
      if (gq + 1 < nks) {                  // prefetch next quantum (3 steps out)
        const float* wp = Wcc + (size_t)(512 + kkl + 32) * 1024 + gnrow;
#pragma unroll
        for (int j = 0; j < 8; j++) fn[j] = wp[(size_t)j * 1024];
      }
      const int w = kkl >> 9, hc = kkl & 511;
      const int wi = (w - gw0)*2;
      float c0[8], c1[8], cb[8];
#pragma unroll
      for (int j = 0; j < 8; j++) {
        c0[j] = wc0[hc+j]; c1[j] = wc1[hc+j]; cb[j] = bcl[hc+j];
      }
#pragma unroll
      for (int bt = 0; bt < 8; bt++) {
        int row = bhalf*128 + bt*16 + l16;
        float x0 = xin[row][wi], x1 = xin[row][wi+1];
        short8 bf;
#pragma unroll
        for (int j = 0; j < 8; j++) {
          float v = fmaf(x0, c0[j], fmaf(x1, c1[j], cb[j]));
          bf[j] = (short)f2bf(fmaxf(v, 0.f));
        }
        gacc[bt] = __builtin_amdgcn_mfma_f32_16x16x32_bf16(af, bf, gacc[bt], 0,0,0);
      }
      gq++;
    }
    gphase = (gphase == 2) ? 0 : gphase + 1;

    if (tid == 0) {
      int need = MEMBERS * (t + 1);
      while (LOAD_CI(ctr) < need) {}
    }
    __syncthreads();   // S4
  }

  // ---- final pred (k=95) from pp of step 190 (pp1 side) ----
  if (member == 0 && tid < 32) {
    int row = tid >> 1, c = tid & 1;
    const float* pps = pp1 + (size_t)team*MEMBERS*32 + row*2 + c;
    float s = c ? bwc1 : bwc0;
#pragma unroll
    for (int m = 0; m < MEMBERS; m++) s += LOAD_CF(pps + m*32);
    out_pred[((size_t)(rbase+row)*96 + 95)*2 + c] = s;
  }

  // ---- write gemm partials ----
  {
    float* pp = partialT + (size_t)kc*262144
              + (size_t)(gnc*32 + nhalf*16 + l4*4)*256 + bhalf*128 + l16;
#pragma unroll
    for (int bt = 0; bt < 8; bt++)
#pragma unroll
      for (int r = 0; r < 4; r++)
        pp[(size_t)r*256 + bt*16] = gacc[bt][r];
  }
}

// ---------------------------------------------------------------------------
// GEMM over K in [0,512): B = warm_out (bf16), A = Wcc[0:512]. 16 blocks.
// ---------------------------------------------------------------------------
__global__ __launch_bounds__(256, 1) void gemm0_kernel(
    const unsigned short* __restrict__ warm, const float* __restrict__ Wcc,
    float* __restrict__ partial8)
{
  const int nc = blockIdx.x;
  const int tid = threadIdx.x;
  const int w = tid >> 6, lane = tid & 63;
  const int l4 = lane >> 4, l16 = lane & 15;

  f32x4 zero = {0.f,0.f,0.f,0.f};
  f32x4 acc[16];
#pragma unroll
  for (int i = 0; i < 16; i++) acc[i] = zero;

  const int nrow = nc*64 + w*16 + l16;
  for (int ks = 0; ks < 16; ks++) {
    const float* wp = Wcc + (size_t)(ks*32 + l4*8) * 1024 + nrow;
    short8 af;
#pragma unroll
    for (int j = 0; j < 8; j++) af[j] = (short)f2bf(wp[(size_t)j * 1024]);
    const unsigned short* cp = warm + ks*32 + l4*8;
#pragma unroll
    for (int bt = 0; bt < 16; bt++) {
      short8 bf = *(const short8*)(cp + (size_t)(bt*16 + l16) * 512);
      acc[bt] = __builtin_amdgcn_mfma_f32_16x16x32_bf16(af, bf, acc[bt], 0,0,0);
    }
  }
  float* pp = partial8 + (size_t)(nc*64 + w*16 + l4*4)*256 + l16;
#pragma unroll
  for (int bt = 0; bt < 16; bt++)
#pragma unroll
    for (int r = 0; r < 4; r++)
      pp[(size_t)r*256 + bt*16] = acc[bt][r];
}

// ctT[n][b] = relu(bcc[n] + sum_{p<8} partialT[p][n][b] + partial8[n][b]);
// also copies the inputs-passthrough output.
__global__ void reduce_kernel(const float* __restrict__ partialT,
                              const float* __restrict__ partial8,
                              const float* __restrict__ bcc, float* __restrict__ ctT,
                              const float* __restrict__ inputs, float* __restrict__ out)
{
  int e = blockIdx.x * 256 + threadIdx.x;   // 1024 blocks
  int n = e >> 8;
  float s = bcc[n] + partial8[e];
#pragma unroll
  for (int p = 0; p < 8; p++) s += partialT[(size_t)p*262144 + e];
  ctT[e] = fmaxf(s, 0.f);
  if (e < 65536) out[49920 + e] = inputs[e];
}

// cost/prob heads: one wave per batch row
__global__ void head_kernel(const float* __restrict__ ctT, const float* __restrict__ Wp,
                            const float* __restrict__ bp, const float* __restrict__ Wco,
                            const float* __restrict__ bco, float* __restrict__ out)
{
  int b = blockIdx.x;
  int lane = threadIdx.x;
  float p0 = 0.f, p1 = 0.f, pc = 0.f;
#pragma unroll
  for (int i = 0; i < 16; i++) {
    int n = i*64 + lane;
    float c = ctT[(size_t)n*256 + b];
    p0 += c * Wp[2*n]; p1 += c * Wp[2*n+1]; pc += c * Wco[n];
  }
  for (int m = 1; m < 64; m <<= 1) {
    p0 += __shfl_xor(p0, m); p1 += __shfl_xor(p1, m); pc += __shfl_xor(pc, m);
  }
  if (lane == 0) {
    out[49152 + b]       = pc + bco[0];
    out[49408 + 2*b]     = 1.f / (1.f + __expf(-(p0 + bp[0])));
    out[49408 + 2*b + 1] = 1.f / (1.f + __expf(-(p1 + bp[1])));
  }
}

// ---------------------------------------------------------------------------
extern "C" void kernel_launch(void* const* d_in, const int* in_sizes, int n_in,
                              void* d_out, int out_size, void* d_ws, size_t ws_size,
                              hipStream_t stream) {
  const float* inputs = (const float*)d_in[0];
  const float* Wk   = (const float*)d_in[1];
  const float* Wr   = (const float*)d_in[2];
  const float* bias = (const float*)d_in[3];
  const float* Ww   = (const float*)d_in[4];
  const float* bw   = (const float*)d_in[5];
  const float* Wc   = (const float*)d_in[6];
  const float* bc   = (const float*)d_in[7];
  const float* Wcc  = (const float*)d_in[8];
  const float* bcc  = (const float*)d_in[9];
  const float* Wp   = (const float*)d_in[10];
  const float* bp   = (const float*)d_in[11];
  const float* Wco  = (const float*)d_in[12];
  const float* bco  = (const float*)d_in[13];
  float* out = (float*)d_out;
  char* ws = (char*)d_ws;

  // ws layout (bytes):
  // [0x000000) h0 256KB | [0x040000) flags 8KB | [0x042000) h1 256KB
  // [0x082000) warm 256KB | [0x0C2000) pp0 32KB | [0x0CA000) pp1 32KB |
  // [0x0D2000) partial8 1MB | [0x8C2000) partialT 8MB | [0x10C2000) ctT 1MB
  unsigned short* h0   = (unsigned short*)(ws);
  int*            flags= (int*)(ws + 0x40000);
  unsigned short* h1   = (unsigned short*)(ws + 0x42000);
  unsigned short* warm = (unsigned short*)(ws + 0x82000);
  float*          pp0  = (float*)(ws + 0xC2000);
  float*          pp1  = (float*)(ws + 0xCA000);
  float*          partial8 = (float*)(ws + 0xD2000);
  float*          partialT = (float*)(ws + 0x8C2000);
  float*          ctT  = (float*)(ws + 0x10C2000);

  // zero h0 + flags (re-done every launch; ws not re-poisoned between replays)
  hipMemsetAsync(d_ws, 0, 0x42000, stream);

  lstm_kernel<<<TEAMS*MEMBERS, 256, 0, stream>>>(inputs, Wk, Wr, bias, Ww, bw,
                                                 Wc, bc, Wcc,
                                                 h0, h1, pp0, pp1, warm, flags,
                                                 partialT, out);
  gemm0_kernel<<<16, 256, 0, stream>>>(warm, Wcc, partial8);
  reduce_kernel<<<1024, 256, 0, stream>>>(partialT, partial8, bcc, ctT, inputs, out);
  head_kernel<<<256, 64, 0, stream>>>(ctT, Wp, bp, Wco, bco, out);
}

// Round 16
// 633.910 us; speedup vs baseline: 1.2995x; 1.0300x over previous
//
#include <hip/hip_runtime.h>
#include <hip/hip_bf16.h>
#include <stdint.h>

// Problem constants
#define B_    256
#define T_    128
#define W_    32
#define H_    512
#define G4_   2048   // 4*H
#define TW_   96     // warm steps
#define STEPS_ 191   // 96 warm + 95 decode cells
#define TEAMS 16
#define MEMBERS 16
#define ROWS  16     // batch rows per team
#define HC    32     // h-columns per block

typedef __attribute__((ext_vector_type(8))) short short8;
typedef __attribute__((ext_vector_type(4))) float f32x4;
typedef __attribute__((ext_vector_type(4))) uint32_t u32x4;

__device__ __forceinline__ unsigned short f2bf(float f) {
  uint32_t u = __float_as_uint(f);
  u += 0x7fffu + ((u >> 16) & 1u);   // round-to-nearest-even
  return (unsigned short)(u >> 16);
}
__device__ __forceinline__ float sigm(float x) { return 1.f / (1.f + __expf(-x)); }
__device__ __forceinline__ float tanh_(float x) { return 1.f - 2.f / (1.f + __expf(2.f * x)); }

// PROVEN (R6) device-scope primitives: compiler agent atomics for the barrier
// protocol; sc0 sc1 asm (early-clobber outputs) only for bulk data.
#define LOAD_CF(p)      __hip_atomic_load((p), __ATOMIC_RELAXED, __HIP_MEMORY_SCOPE_AGENT)
#define LOAD_CI(p)      __hip_atomic_load((p), __ATOMIC_RELAXED, __HIP_MEMORY_SCOPE_AGENT)
#define ARRIVE(p)       __hip_atomic_fetch_add((p), 1, __ATOMIC_RELAXED, __HIP_MEMORY_SCOPE_AGENT)

__device__ __forceinline__ u32x4 ld16c(const void* p) {
  u32x4 v;
  asm volatile("global_load_dwordx4 %0, %1, off sc0 sc1"
               : "=&v"(v) : "v"(p) : "memory");
  return v;   // caller batches, then s_waitcnt vmcnt(0) + sched_barrier
}
__device__ __forceinline__ void st16c(void* p, u32x4 v) {
  asm volatile("global_store_dwordx4 %0, %1, off sc0 sc1" :: "v"(p), "v"(v) : "memory");
}
__device__ __forceinline__ void stf16c(void* p, f32x4 v) {
  asm volatile("global_store_dwordx4 %0, %1, off sc0 sc1" :: "v"(p), "v"(v) : "memory");
}

// --- GEMM sub-quantum macros: compile-time bt indices (no dynamic gacc idx) ---
#define GBT_RELU(C0, C1)                                                      \
  {                                                                           \
    const int kkl_ = gK - 512 + l4*8;                                         \
    const int hc_ = kkl_ & 511;                                               \
    const int wi_ = ((kkl_ >> 9) - gw0) * 2;                                  \
    {                                                                         \
      int row_ = bhalf*128 + (C0)*16 + l16;                                   \
      float x0_ = xin[row_][wi_], x1_ = xin[row_][wi_+1];                     \
      short8 bf_;                                                             \
      _Pragma("unroll")                                                       \
      for (int j = 0; j < 8; j++) {                                           \
        float v_ = fmaf(x0_, wc0[hc_+j], fmaf(x1_, wc1[hc_+j], bcl[hc_+j]));  \
        bf_[j] = (short)f2bf(fmaxf(v_, 0.f));                                 \
      }                                                                       \
      gacc[C0] = __builtin_amdgcn_mfma_f32_16x16x32_bf16(af, bf_, gacc[C0], 0,0,0); \
    }                                                                         \
    {                                                                         \
      int row_ = bhalf*128 + (C1)*16 + l16;                                   \
      float x0_ = xin[row_][wi_], x1_ = xin[row_][wi_+1];                     \
      short8 bf_;                                                             \
      _Pragma("unroll")                                                       \
      for (int j = 0; j < 8; j++) {                                           \
        float v_ = fmaf(x0_, wc0[hc_+j], fmaf(x1_, wc1[hc_+j], bcl[hc_+j]));  \
        bf_[j] = (short)f2bf(fmaxf(v_, 0.f));                                 \
      }                                                                       \
      gacc[C1] = __builtin_amdgcn_mfma_f32_16x16x32_bf16(af, bf_, gacc[C1], 0,0,0); \
    }                                                                         \
  }

#define GBT_WARM(C0, C1)                                                      \
  {                                                                           \
    const unsigned short* wb_ = warm + gK + l4*8;                             \
    u32x4 wv0_ = ld16c(wb_ + (size_t)(bhalf*128 + (C0)*16 + l16) * 512);      \
    u32x4 wv1_ = ld16c(wb_ + (size_t)(bhalf*128 + (C1)*16 + l16) * 512);      \
    asm volatile("s_waitcnt vmcnt(0)" ::: "memory");                          \
    __builtin_amdgcn_sched_barrier(0);                                        \
    short8 b0_ = *(const short8*)&wv0_;                                       \
    short8 b1_ = *(const short8*)&wv1_;                                       \
    gacc[C0] = __builtin_amdgcn_mfma_f32_16x16x32_bf16(af, b0_, gacc[C0], 0,0,0); \
    gacc[C1] = __builtin_amdgcn_mfma_f32_16x16x32_bf16(af, b1_, gacc[C1], 0,0,0); \
  }

// ---------------------------------------------------------------------------
// Persistent LSTM (R6 protocol) + GEMM spread as 2+2 bt sub-quanta per step
// in the load-shadow and poll-shadow. Each block owns one (kc,gnc) slice;
// kc==0 blocks additionally cover K in [0,512) with B = warm_out (coherent),
// guarded by a one-time global counter (all blocks past t=95).
// ---------------------------------------------------------------------------
__global__ __launch_bounds__(256, 1) void lstm_kernel(
    const float* __restrict__ inputs, const float* __restrict__ Wk,
    const float* __restrict__ Wr, const float* __restrict__ bias,
    const float* __restrict__ Ww, const float* __restrict__ bw,
    const float* __restrict__ Wc, const float* __restrict__ bc,
    const float* __restrict__ Wcc,
    unsigned short* __restrict__ h0buf, unsigned short* __restrict__ h1buf,
    float* __restrict__ pp0, float* __restrict__ pp1,
    unsigned short* __restrict__ warm, int* __restrict__ flags,
    float* __restrict__ partialT, float* __restrict__ out_pred)
{
  const int team = blockIdx.x & 15;
  const int member = blockIdx.x >> 4;   // 0..15
  const int rbase = team * ROWS;
  const int hbase = member * HC;
  const int tid = threadIdx.x;
  const int wave = tid >> 6;
  const int lane = tid & 63;
  const int l4 = lane >> 4, l16 = lane & 15;

  __shared__ unsigned short h_lds[ROWS][H_];              // 16KB, XOR swizzled
  __shared__ float x_all[TW_][ROWS][2];                   // 12KB warm inputs
  __shared__ float x_lds[ROWS][2];                        // decode x (pred)
  __shared__ float pp_lds[4][ROWS][2];                    // per-wave partials
  __shared__ alignas(16) unsigned short h_out[ROWS][HC];  // 1KB repack
  __shared__ float wc0[512], wc1[512], bcl[512];          // 6KB gemm tables
  __shared__ float xin[256][10];                          // 10KB gemm x pairs

  // ---- gemm slice for this block ----
  const int kc = blockIdx.x >> 5, gnc = blockIdx.x & 31;
  const bool iskc0 = (kc == 0);
  const int gw0 = iskc0 ? 0 : kc*4 - 1;

  for (int i = tid; i < TW_*ROWS*2; i += 256) {
    int tt = i >> 5, row = (i >> 1) & 15, c = i & 1;
    x_all[tt][row][c] = inputs[(size_t)(rbase+row)*(T_*2) + (W_+tt)*2 + c];
  }
  for (int i = tid; i < 512; i += 256) {
    wc0[i] = Wc[i]; wc1[i] = Wc[512 + i]; bcl[i] = bc[i];
  }
  for (int i = tid; i < 2560; i += 256) {
    int row = i / 10, r = i - row*10;
    xin[row][r] = inputs[(size_t)row*(T_*2) + gw0*2 + r];
  }

  const int gateL = l16 & 3, hclL = l16 >> 2;
  short8 afrag[2][16];          // Wr^T fragments: 128 VGPRs
  float bbv[2][4], wk0v[2][4], wk1v[2][4], wwv[2][2];
#pragma unroll
  for (int a = 0; a < 2; a++) {
    const int gcA = gateL*H_ + hbase + wave*8 + a*4 + hclL;
#pragma unroll
    for (int ks = 0; ks < 16; ks++) {
      const float* wp = Wr + (size_t)(ks*32 + l4*8) * G4_ + gcA;
#pragma unroll
      for (int j = 0; j < 8; j++) afrag[a][ks][j] = (short)f2bf(wp[(size_t)j * G4_]);
    }
    const int colA = hbase + wave*8 + a*4 + l4;
#pragma unroll
    for (int j = 0; j < 4; j++) {
      int gcj = j*H_ + colA;
      bbv[a][j] = bias[gcj]; wk0v[a][j] = Wk[gcj]; wk1v[a][j] = Wk[G4_ + gcj];
    }
    wwv[a][0] = Ww[2*colA]; wwv[a][1] = Ww[2*colA + 1];
  }
  const float bwc0 = bw[0], bwc1 = bw[1];
  float creg[2] = {0.f, 0.f};

  // ---- gemm per-wave state (64 kkl slices of K=32; kc0: last 16 = warm-B) --
  auto KIDX = [&](int g) -> int {
    return iskc0 ? (g < 48 ? 512 + g*32 : (g - 48)*32) : kc*2048 + g*32;
  };
  const int nhalf = wave & 1, bhalf = wave >> 1;
  const int gnrow = gnc*32 + nhalf*16 + l16;
  f32x4 gacc[8];
#pragma unroll
  for (int i = 0; i < 8; i++) gacc[i] = (f32x4){0.f,0.f,0.f,0.f};
  short8 af;
  float fn[8];
  {
    const float* wp = Wcc + (size_t)(KIDX(0) + l4*8) * 1024 + gnrow;   // FIX: +l4*8
#pragma unroll
    for (int j = 0; j < 8; j++) fn[j] = wp[(size_t)j * 1024];
  }
  int gq = -1, gK = 0, phase = 1;
  __syncthreads();

  int* ctr = flags + team * 16;                 // 64B-spaced step counter
  int* gctr2 = flags + 256;                     // global "past t=95" counter
  const int srow = tid >> 4, sg = tid & 15;     // h-stage: 16 thr/row, 4x16B

  for (int t = 0; t < STEPS_; t++) {
    const unsigned short* hprev = (t & 1) ? h1buf : h0buf;
    unsigned short* hnext = (t & 1) ? h0buf : h1buf;
    const float* ppprev = (t & 1) ? pp1 : pp0;
    float* ppnext = (t & 1) ? pp0 : pp1;

    // ---- phase A: issue ALL coherent loads; GEMM work fills load-shadow ----
    const bool dox = (t >= TW_) && (tid < 32);
    float vals[MEMBERS];
    if (dox) {
      int row = tid >> 1, c = tid & 1;
      const float* pps = ppprev + (size_t)team*MEMBERS*32 + row*2 + c;
#pragma unroll
      for (int m = 0; m < MEMBERS; m++) vals[m] = LOAD_CF(pps + m*32);
    }
    u32x4 q[4];
    {
      const unsigned short* srcb = hprev + (size_t)(rbase+srow)*H_ + sg*8;
#pragma unroll
      for (int i = 0; i < 4; i++) q[i] = ld16c(srcb + i*128);   // granule sg+16i
    }
    if (gq >= 0 && gq < 64) {                    // load-shadow sub-quantum
      if (gK < 512) { if (!phase) GBT_WARM(0,1) else GBT_WARM(4,5) }
      else          { if (!phase) GBT_RELU(0,1) else GBT_RELU(4,5) }
    }
    asm volatile("s_waitcnt vmcnt(0)" ::: "memory");
    __builtin_amdgcn_sched_barrier(0);
#pragma unroll
    for (int i = 0; i < 4; i++)
      *(u32x4*)&h_lds[srow][((sg + 16*i) ^ (srow & 7)) * 8] = q[i];
    if (dox) {
      int row = tid >> 1, c = tid & 1;
      float s = c ? bwc1 : bwc0;
#pragma unroll
      for (int m = 0; m < MEMBERS; m++) s += vals[m];
      x_lds[row][c] = s;
      if (member == 0)
        out_pred[((size_t)(rbase+row)*96 + (t - TW_))*2 + c] = s;
    }
    __syncthreads();   // S1

    // ---- phase B: z^T = Wr^T @ h^T (+ bias + Wk*x), MFMA over K=512 ----
    f32x4 acc[2];
    const float* xsrc = (t < TW_) ? &x_all[t][0][0] : &x_lds[0][0];
    {
      float x0 = xsrc[2*l16], x1 = xsrc[2*l16 + 1];
#pragma unroll
      for (int a = 0; a < 2; a++)
#pragma unroll
        for (int j = 0; j < 4; j++)
          acc[a][j] = bbv[a][j] + wk0v[a][j]*x0 + wk1v[a][j]*x1;
    }
#pragma unroll
    for (int ks = 0; ks < 16; ks++) {
      int pg = ((ks*4 + l4) ^ (l16 & 7)) * 8;
      short8 b0 = *(const short8*)&h_lds[l16][pg];
      acc[0] = __builtin_amdgcn_mfma_f32_16x16x32_bf16(afrag[0][ks], b0, acc[0], 0,0,0);
      acc[1] = __builtin_amdgcn_mfma_f32_16x16x32_bf16(afrag[1][ks], b0, acc[1], 0,0,0);
    }

    // ---- phase C: in-register cell update -> h_out + pred partials ----
    float pp0v = 0.f, pp1v = 0.f;
#pragma unroll
    for (int a = 0; a < 2; a++) {
      float zi = acc[a][0], zf = acc[a][1], zg = acc[a][2], zo = acc[a][3];
      float cn = sigm(zf)*creg[a] + sigm(zi)*tanh_(zg);
      float hn = sigm(zo)*tanh_(cn);
      creg[a] = cn;
      pp0v += hn * wwv[a][0];
      pp1v += hn * wwv[a][1];
      h_out[l16][wave*8 + a*4 + l4] = f2bf(hn);
    }
    if (t >= TW_ - 1) {
      pp0v += __shfl_xor(pp0v, 16); pp0v += __shfl_xor(pp0v, 32);
      pp1v += __shfl_xor(pp1v, 16); pp1v += __shfl_xor(pp1v, 32);
      if (l4 == 0) {
        pp_lds[wave][l16][0] = pp0v;
        pp_lds[wave][l16][1] = pp1v;
      }
    }
    __syncthreads();   // S2

    // ---- phase D: coalesced coherent stores ----
    if (tid < 64) {                        // h: 16 rows x 64B, 16B/lane
      int row = tid >> 2, qd = tid & 3;
      u32x4 v = *(const u32x4*)&h_out[row][qd*8];
      st16c(hnext + (size_t)(rbase+row)*H_ + hbase + qd*8, v);
      if (t == TW_ - 1)
        st16c(warm + (size_t)(rbase+row)*H_ + hbase + qd*8, v);  // coherent!
    }
    if (t >= TW_ - 1 && tid < 8) {         // pp: 128B contiguous per block
      f32x4 pv;
#pragma unroll
      for (int j = 0; j < 4; j++) {
        int idx = tid*4 + j, row = idx >> 1, c = idx & 1;
        pv[j] = pp_lds[0][row][c] + pp_lds[1][row][c]
              + pp_lds[2][row][c] + pp_lds[3][row][c];
      }
      stf16c(ppnext + (size_t)(team*MEMBERS + member)*32 + tid*4, pv);
    }

    // ---- barrier: drain, arrive; GEMM fills poll-shadow; advance; poll ----
    asm volatile("s_waitcnt vmcnt(0)" ::: "memory");
    __syncthreads();   // S3: every wave's stores at the coherence point
    if (tid == 0) {
      ARRIVE(ctr);
      if (t == TW_ - 1) ARRIVE(gctr2);
    }
    if (gq >= 0 && gq < 64) {                    // poll-shadow sub-quantum
      if (gK < 512) { if (!phase) GBT_WARM(2,3) else GBT_WARM(6,7) }
      else          { if (!phase) GBT_RELU(2,3) else GBT_RELU(6,7) }
    }
    if (phase) {                                 // advance kkl every 2nd step
      if (gq + 1 < 64) {
        gq++;
        gK = KIDX(gq);
#pragma unroll
        for (int j = 0; j < 8; j++) af[j] = (short)f2bf(fn[j]);
        if (iskc0 && gq == 48) {                 // warm-B guard: all past t=95
          if (tid == 0) { while (LOAD_CI(gctr2) < 256) {} }
          __syncthreads();
        }
        if (gq + 1 < 64) {
          const float* wp = Wcc + (size_t)(KIDX(gq + 1) + l4*8) * 1024 + gnrow;  // FIX: +l4*8
#pragma unroll
          for (int j = 0; j < 8; j++) fn[j] = wp[(size_t)j * 1024];
        }
      } else {
        gq = 64;                                 // done sentinel
      }
    }
    phase ^= 1;
    if (tid == 0) {
      int need = MEMBERS * (t + 1);
      while (LOAD_CI(ctr) < need) {}
    }
    __syncthreads();   // S4
  }

  // ---- final pred (k=95) from pp of step 190 (pp1 side) ----
  if (member == 0 && tid < 32) {
    int row = tid >> 1, c = tid & 1;
    const float* pps = pp1 + (size_t)team*MEMBERS*32 + row*2 + c;
    float s = c ? bwc1 : bwc0;
#pragma unroll
    for (int m = 0; m < MEMBERS; m++) s += LOAD_CF(pps + m*32);
    out_pred[((size_t)(rbase+row)*96 + 95)*2 + c] = s;
  }

  // ---- write gemm partials (kc0 includes K[0,2048); others K slice) ----
  {
    float* pp = partialT + (size_t)kc*262144
              + (size_t)(gnc*32 + nhalf*16 + l4*4)*256 + bhalf*128 + l16;
#pragma unroll
    for (int bt = 0; bt < 8; bt++)
#pragma unroll
      for (int r = 0; r < 4; r++)
        pp[(size_t)r*256 + bt*16] = gacc[bt][r];
  }
}

// ctT[n][b] = relu(bcc[n] + sum_p partialT[p][n][b]); also copies the
// inputs-passthrough output.
__global__ void reduce_kernel(const float* __restrict__ partialT,
                              const float* __restrict__ bcc, float* __restrict__ ctT,
                              const float* __restrict__ inputs, float* __restrict__ out)
{
  int e = blockIdx.x * 256 + threadIdx.x;   // 1024 blocks
  int n = e >> 8;
  float s = bcc[n];
#pragma unroll
  for (int p = 0; p < 8; p++) s += partialT[(size_t)p*262144 + e];
  ctT[e] = fmaxf(s, 0.f);
  if (e < 65536) out[49920 + e] = inputs[e];
}

// cost/prob heads: one wave per batch row
__global__ void head_kernel(const float* __restrict__ ctT, const float* __restrict__ Wp,
                            const float* __restrict__ bp, const float* __restrict__ Wco,
                            const float* __restrict__ bco, float* __restrict__ out)
{
  int b = blockIdx.x;
  int lane = threadIdx.x;
  float p0 = 0.f, p1 = 0.f, pc = 0.f;
#pragma unroll
  for (int i = 0; i < 16; i++) {
    int n = i*64 + lane;
    float c = ctT[(size_t)n*256 + b];
    p0 += c * Wp[2*n]; p1 += c * Wp[2*n+1]; pc += c * Wco[n];
  }
  for (int m = 1; m < 64; m <<= 1) {
    p0 += __shfl_xor(p0, m); p1 += __shfl_xor(p1, m); pc += __shfl_xor(pc, m);
  }
  if (lane == 0) {
    out[49152 + b]       = pc + bco[0];
    out[49408 + 2*b]     = 1.f / (1.f + __expf(-(p0 + bp[0])));
    out[49408 + 2*b + 1] = 1.f / (1.f + __expf(-(p1 + bp[1])));
  }
}

// ---------------------------------------------------------------------------
extern "C" void kernel_launch(void* const* d_in, const int* in_sizes, int n_in,
                              void* d_out, int out_size, void* d_ws, size_t ws_size,
                              hipStream_t stream) {
  const float* inputs = (const float*)d_in[0];
  const float* Wk   = (const float*)d_in[1];
  const float* Wr   = (const float*)d_in[2];
  const float* bias = (const float*)d_in[3];
  const float* Ww   = (const float*)d_in[4];
  const float* bw   = (const float*)d_in[5];
  const float* Wc   = (const float*)d_in[6];
  const float* bc   = (const float*)d_in[7];
  const float* Wcc  = (const float*)d_in[8];
  const float* bcc  = (const float*)d_in[9];
  const float* Wp   = (const float*)d_in[10];
  const float* bp   = (const float*)d_in[11];
  const float* Wco  = (const float*)d_in[12];
  const float* bco  = (const float*)d_in[13];
  float* out = (float*)d_out;
  char* ws = (char*)d_ws;

  // ws layout (bytes):
  // [0x000000) h0 256KB | [0x040000) flags 8KB | [0x042000) h1 256KB
  // [0x082000) warm 256KB | [0x0C2000) pp0 32KB | [0x0CA000) pp1 32KB |
  // [0x8C2000) partialT 8MB | [0x10C2000) ctT 1MB
  unsigned short* h0   = (unsigned short*)(ws);
  int*            flags= (int*)(ws + 0x40000);
  unsigned short* h1   = (unsigned short*)(ws + 0x42000);
  unsigned short* warm = (unsigned short*)(ws + 0x82000);
  float*          pp0  = (float*)(ws + 0xC2000);
  float*          pp1  = (float*)(ws + 0xCA000);
  float*          partialT = (float*)(ws + 0x8C2000);
  float*          ctT  = (float*)(ws + 0x10C2000);

  // zero h0 + flags (re-done every launch; ws not re-poisoned between replays)
  hipMemsetAsync(d_ws, 0, 0x42000, stream);

  lstm_kernel<<<TEAMS*MEMBERS, 256, 0, stream>>>(inputs, Wk, Wr, bias, Ww, bw,
                                                 Wc, bc, Wcc,
                                                 h0, h1, pp0, pp1, warm, flags,
                                                 partialT, out);
  reduce_kernel<<<1024, 256, 0, stream>>>(partialT, bcc, ctT, inputs, out);
  head_kernel<<<256, 64, 0, stream>>>(ctT, Wp, bp, Wco, bco, out);
}